// Round 1
// baseline (1366.488 us; speedup 1.0000x reference)
//
#include <hip/hip_runtime.h>
#include <hip/hip_bf16.h>
#include <stdint.h>

#define BB  2
#define LL  4096
#define DM  256
#define DI  512
#define NST 16
#define DTR 16
#define DFF 2048
#define ML  (BB*LL)   // 8192 rows

typedef __attribute__((ext_vector_type(8))) short s16x8;
typedef __attribute__((ext_vector_type(4))) float f32x4;

__device__ __forceinline__ ushort f2bf(float f) {
  union { float f; uint32_t u; } v; v.f = f;
  return (ushort)((v.u + 0x7FFFu + ((v.u >> 16) & 1u)) >> 16);  // RNE
}

__device__ __forceinline__ void async16(const void* g, void* l) {
  __builtin_amdgcn_global_load_lds(
      (const __attribute__((address_space(1))) void*)g,
      (__attribute__((address_space(3))) void*)l, 16, 0, 0);
}

// ---------------- generic f32 -> bf16 convert (n4 = count/4) ----------------
__global__ void k_f2b(const float* __restrict__ src, ushort* __restrict__ dst, int n4) {
  int i = blockIdx.x * 256 + threadIdx.x;
  if (i >= n4) return;
  f32x4 v = ((const f32x4*)src)[i];
  *(ushort4*)&dst[i * 4] = make_ushort4(f2bf(v[0]), f2bf(v[1]), f2bf(v[2]), f2bf(v[3]));
}

// ---------------- x_proj_w [48][512] -> padded bf16 [128][512] --------------
__global__ void k_xprojw(const float* __restrict__ src, ushort* __restrict__ dst) {
  int i = blockIdx.x * 256 + threadIdx.x;         // ushort4 groups: 128*512/4
  if (i >= 128 * DI / 4) return;
  int e = i * 4;
  int r = e >> 9;          // /512
  int c = e & 511;
  ushort4 o;
  if (r < DTR + 2 * NST) {
    f32x4 v = *(const f32x4*)&src[r * DI + c];
    o = make_ushort4(f2bf(v[0]), f2bf(v[1]), f2bf(v[2]), f2bf(v[3]));
  } else {
    o = make_ushort4(0, 0, 0, 0);
  }
  *(ushort4*)&dst[e] = o;
}

// ---------------- bf16 MFMA GEMM: out[M][N] = A[M][K] @ W[N][K]^T -----------
// 128x128 tile, 4 waves (2x2, 64x64 each), BK=32, global_load_lds staging with
// 16B-chunk XOR swizzle (chunk ^= row&3) so fragment ds_read_b128 is 2-way (free).
template<int OUTF, int OUTB, int BIAS, int RELU>
__global__ __launch_bounds__(256)
void k_gemm(const ushort* __restrict__ A, const ushort* __restrict__ W,
            const float* __restrict__ bias,
            float* __restrict__ outF, ushort* __restrict__ outB,
            int M, int N, int K) {
  __shared__ __align__(16) ushort As[128 * 32];
  __shared__ __align__(16) ushort Bs[128 * 32];
  const int tid  = threadIdx.x;
  const int lane = tid & 63;
  const int wv   = tid >> 6;
  const int m0 = blockIdx.y << 7;
  const int n0 = blockIdx.x << 7;
  const int wr = (wv >> 1) << 6;
  const int wc = (wv & 1) << 6;
  const int lr = lane & 15;
  const int hi = lane >> 4;

  f32x4 acc[4][4] = {};

  const int sr0 = (wv << 5) + (lane >> 2);   // staging row (this wave: rows wv*32..+31)
  const int sc  = lane & 3;                  // 16B chunk within 32-elem row

  for (int k0 = 0; k0 < K; k0 += 32) {
#pragma unroll
    for (int j = 0; j < 2; ++j) {
      const int r  = sr0 + j * 16;
      const int cs = sc ^ (r & 3);           // pre-swizzled global source chunk
      async16(A + (size_t)(m0 + r) * K + k0 + cs * 8, &As[((wv << 5) + j * 16) * 32]);
      async16(W + (size_t)(n0 + r) * K + k0 + cs * 8, &Bs[((wv << 5) + j * 16) * 32]);
    }
    __syncthreads();   // compiler emits vmcnt(0) drain before barrier

    s16x8 af[4], bf_[4];
#pragma unroll
    for (int mi = 0; mi < 4; ++mi) {
      const int row = wr + mi * 16 + lr;
      af[mi] = *(const s16x8*)&As[row * 32 + ((hi ^ (row & 3)) << 3)];
    }
#pragma unroll
    for (int ni = 0; ni < 4; ++ni) {
      const int row = wc + ni * 16 + lr;
      bf_[ni] = *(const s16x8*)&Bs[row * 32 + ((hi ^ (row & 3)) << 3)];
    }
#pragma unroll
    for (int mi = 0; mi < 4; ++mi)
#pragma unroll
      for (int ni = 0; ni < 4; ++ni)
        acc[mi][ni] = __builtin_amdgcn_mfma_f32_16x16x32_bf16(af[mi], bf_[ni], acc[mi][ni], 0, 0, 0);
    __syncthreads();
  }

#pragma unroll
  for (int mi = 0; mi < 4; ++mi) {
#pragma unroll
    for (int ni = 0; ni < 4; ++ni) {
      const int gc = n0 + wc + ni * 16 + lr;           // C/D: col = lane&15
      const float b = BIAS ? bias[gc] : 0.f;
#pragma unroll
      for (int i = 0; i < 4; ++i) {
        const int gr = m0 + wr + mi * 16 + (hi << 2) + i;  // row = (lane>>4)*4+reg
        float v = acc[mi][ni][i] + b;
        if (RELU) v = fmaxf(v, 0.f);
        if (OUTF) outF[(size_t)gr * N + gc] = v;
        if (OUTB) outB[(size_t)gr * N + gc] = f2bf(v);
      }
    }
  }
}

// ---------------- causal depthwise conv (k=4) + SiLU ------------------------
// xz[ML][1024]; xin = cols 0..511. Writes u (f32) and u_bf (bf16).
__global__ void k_conv(const float* __restrict__ xz, const float* __restrict__ cw,
                       const float* __restrict__ cb,
                       float* __restrict__ u, ushort* __restrict__ u_bf) {
  const int i = blockIdx.x * 256 + threadIdx.x;    // over ML*DI/4
  if (i >= ML * DI / 4) return;
  const int d4 = i & (DI / 4 - 1);
  const int bl = i / (DI / 4);
  const int l  = bl & (LL - 1);
  const int d  = d4 << 2;
  f32x4 acc;
  acc[0] = cb[d]; acc[1] = cb[d + 1]; acc[2] = cb[d + 2]; acc[3] = cb[d + 3];
#pragma unroll
  for (int j = 0; j < 4; ++j) {
    const int lj = l - 3 + j;
    if (lj >= 0) {
      const f32x4 xv = *(const f32x4*)&xz[(size_t)(bl + j - 3) * 1024 + d];
      acc[0] += xv[0] * cw[(d + 0) * 4 + j];
      acc[1] += xv[1] * cw[(d + 1) * 4 + j];
      acc[2] += xv[2] * cw[(d + 2) * 4 + j];
      acc[3] += xv[3] * cw[(d + 3) * 4 + j];
    }
  }
  f32x4 o;
#pragma unroll
  for (int c = 0; c < 4; ++c) o[c] = acc[c] / (1.f + __expf(-acc[c]));
  *(f32x4*)&u[(size_t)bl * DI + d] = o;
  *(ushort4*)&u_bf[(size_t)bl * DI + d] =
      make_ushort4(f2bf(o[0]), f2bf(o[1]), f2bf(o[2]), f2bf(o[3]));
}

// ---------------- delta = softplus(dt @ dt_proj_w^T + b), K=16 --------------
__global__ void k_dtproj(const float* __restrict__ xdbl, const float* __restrict__ w,
                         const float* __restrict__ bias, float* __restrict__ delta) {
  const int m = blockIdx.x;
  const int tid = threadIdx.x;
  __shared__ float sdt[16];
  if (tid < 16) sdt[tid] = xdbl[(size_t)m * 128 + tid];
  __syncthreads();
#pragma unroll
  for (int rep = 0; rep < 2; ++rep) {
    const int nn = tid + rep * 256;
    float acc = bias[nn];
#pragma unroll
    for (int k = 0; k < 16; ++k) acc += sdt[k] * w[nn * 16 + k];
    delta[(size_t)m * DI + nn] = (acc > 15.f) ? acc : log1pf(__expf(acc));
  }
}

// ---------------- selective scan + gating epilogue --------------------------
// block = 256 thr = 16 d x 16 n; grid = B*32. Writes y_bf = ((scan+u*D)*silu(z)).
__global__ __launch_bounds__(256)
void k_scan(const float* __restrict__ delta, const float* __restrict__ u,
            const float* __restrict__ xdbl, const float* __restrict__ xz,
            const float* __restrict__ A_log, const float* __restrict__ Dp,
            ushort* __restrict__ y_bf) {
  const int b  = blockIdx.x >> 5;
  const int d0 = (blockIdx.x & 31) << 4;
  const int tid = threadIdx.x;
  const int dl = tid >> 4;
  const int n  = tid & 15;
  const int d  = d0 + dl;
  const float Adn = -__expf(A_log[d * NST + n]);
  const float Dd  = Dp[d];
  float h = 0.f;
  __shared__ float sdelta[64][16], su[64][16], sB[64][16], sC[64][16], sz[64][16];
  __shared__ ushort sy[64][16];
  const size_t base = (size_t)b * LL;
  const int row = tid >> 4, col = tid & 15;

  for (int tc = 0; tc < LL; tc += 64) {
#pragma unroll
    for (int i = 0; i < 4; ++i) {
      const int r = (i << 4) + row;
      const size_t g = base + tc + r;
      sdelta[r][col] = delta[g * DI + d0 + col];
      su[r][col]     = u[g * DI + d0 + col];
      sB[r][col]     = xdbl[g * 128 + DTR + col];
      sC[r][col]     = xdbl[g * 128 + DTR + NST + col];
      sz[r][col]     = xz[g * 1024 + DI + d0 + col];
    }
    __syncthreads();
#pragma unroll 4
    for (int t = 0; t < 64; ++t) {
      const float dt = sdelta[t][dl];
      const float ut = su[t][dl];
      const float dA = __expf(dt * Adn);
      h = dA * h + dt * sB[t][n] * ut;
      float yc = h * sC[t][n];
      yc += __shfl_xor(yc, 1, 16);
      yc += __shfl_xor(yc, 2, 16);
      yc += __shfl_xor(yc, 4, 16);
      yc += __shfl_xor(yc, 8, 16);
      if (n == 0) {
        const float zt = sz[t][dl];
        sy[t][dl] = f2bf((yc + ut * Dd) * (zt / (1.f + __expf(-zt))));
      }
    }
    __syncthreads();
#pragma unroll
    for (int i = 0; i < 4; ++i) {
      const int r = (i << 4) + row;
      y_bf[(base + tc + r) * DI + d0 + col] = sy[r][col];
    }
  }
}

// ---------------------------------------------------------------------------
extern "C" void kernel_launch(void* const* d_in, const int* in_sizes, int n_in,
                              void* d_out, int out_size, void* d_ws, size_t ws_size,
                              hipStream_t stream) {
  const float* x          = (const float*)d_in[0];
  const float* in_proj_w  = (const float*)d_in[1];
  const float* conv_w     = (const float*)d_in[2];
  const float* conv_b     = (const float*)d_in[3];
  const float* x_proj_w   = (const float*)d_in[4];
  const float* dt_proj_w  = (const float*)d_in[5];
  const float* dt_proj_b  = (const float*)d_in[6];
  const float* A_log      = (const float*)d_in[7];
  const float* Dp         = (const float*)d_in[8];
  const float* out_proj_w = (const float*)d_in[9];
  const float* lin1_w     = (const float*)d_in[10];
  const float* lin1_b     = (const float*)d_in[11];
  const float* lin2_w     = (const float*)d_in[12];
  const float* lin2_b     = (const float*)d_in[13];
  float* out = (float*)d_out;

  char* p = (char*)d_ws;
  auto carve = [&](size_t bytes) -> char* {
    char* r = p;
    p += (bytes + 255) & ~(size_t)255;
    return r;
  };
  ushort* x_bf   = (ushort*)carve((size_t)ML * DM * 2);
  ushort* wip_bf = (ushort*)carve((size_t)2 * DI * DM * 2);
  float*  xz     = (float*) carve((size_t)ML * 1024 * 4);
  float*  u      = (float*) carve((size_t)ML * DI * 4);
  ushort* u_bf   = (ushort*)carve((size_t)ML * DI * 2);
  ushort* xpw_bf = (ushort*)carve((size_t)128 * DI * 2);
  float*  xdbl   = (float*) carve((size_t)ML * 128 * 4);
  float*  delta  = (float*) carve((size_t)ML * DI * 4);
  ushort* y_bf   = (ushort*)carve((size_t)ML * DI * 2);
  ushort* opw_bf = (ushort*)carve((size_t)DM * DI * 2);
  // lifetime-disjoint aliases (all writes happen after the donor's last read):
  ushort* m_bf   = u_bf;            // u_bf last read by x_proj gemm
  ushort* h1_bf  = (ushort*)xz;     // xz last read by scan (z)
  ushort* l1w_bf = (ushort*)delta;  // delta last read by scan
  ushort* l2w_bf = (ushort*)u;      // u last read by scan

  // 1) convert x and in_proj_w to bf16
  k_f2b<<<(ML * DM / 4 + 255) / 256, 256, 0, stream>>>(x, x_bf, ML * DM / 4);
  k_f2b<<<(2 * DI * DM / 4 + 255) / 256, 256, 0, stream>>>(in_proj_w, wip_bf, 2 * DI * DM / 4);
  // 2) xz = x @ in_proj_w^T   (M=8192, N=1024, K=256)  -> f32
  k_gemm<1, 0, 0, 0><<<dim3(1024 / 128, ML / 128), 256, 0, stream>>>(
      x_bf, wip_bf, nullptr, xz, nullptr, ML, 1024, DM);
  // 3) causal conv + SiLU -> u (f32 + bf16)
  k_conv<<<(ML * DI / 4 + 255) / 256, 256, 0, stream>>>(xz, conv_w, conv_b, u, u_bf);
  // 4) x_dbl = u @ x_proj_w^T (N padded 48->128, zero rows)  -> f32
  k_xprojw<<<(128 * DI / 4 + 255) / 256, 256, 0, stream>>>(x_proj_w, xpw_bf);
  k_gemm<1, 0, 0, 0><<<dim3(1, ML / 128), 256, 0, stream>>>(
      u_bf, xpw_bf, nullptr, xdbl, nullptr, ML, 128, DI);
  // 5) delta = softplus(dt @ dt_proj_w^T + b)
  k_dtproj<<<ML, 256, 0, stream>>>(xdbl, dt_proj_w, dt_proj_b, delta);
  // 6) selective scan + gating -> y_bf
  k_scan<<<BB * 32, 256, 0, stream>>>(delta, u, xdbl, xz, A_log, Dp, y_bf);
  // 7) m = y @ out_proj_w^T (N=256, K=512) -> bf16
  k_f2b<<<(DM * DI / 4 + 255) / 256, 256, 0, stream>>>(out_proj_w, opw_bf, DM * DI / 4);
  k_gemm<0, 1, 0, 0><<<dim3(DM / 128, ML / 128), 256, 0, stream>>>(
      y_bf, opw_bf, nullptr, nullptr, m_bf, ML, DM, DI);
  // 8) h1 = relu(m @ lin1_w^T + b1) (N=2048, K=256) -> bf16
  k_f2b<<<(DFF * DM / 4 + 255) / 256, 256, 0, stream>>>(lin1_w, l1w_bf, DFF * DM / 4);
  k_gemm<0, 1, 1, 1><<<dim3(DFF / 128, ML / 128), 256, 0, stream>>>(
      m_bf, l1w_bf, lin1_b, nullptr, h1_bf, ML, DFF, DM);
  // 9) out = h1 @ lin2_w^T + b2 (N=2048, K=2048) -> f32 to d_out
  k_f2b<<<(DFF * DFF / 4 + 255) / 256, 256, 0, stream>>>(lin2_w, l2w_bf, DFF * DFF / 4);
  k_gemm<1, 0, 1, 0><<<dim3(DFF / 128, ML / 128), 256, 0, stream>>>(
      h1_bf, l2w_bf, lin2_b, out, nullptr, ML, DFF, DFF);
}

// Round 4
// 393.086 us; speedup vs baseline: 3.4763x; 3.4763x over previous
//
#include <hip/hip_runtime.h>
#include <hip/hip_bf16.h>
#include <stdint.h>

#define BB  2
#define LL  4096
#define DM  256
#define DI  512
#define NST 16
#define DTR 16
#define DFF 2048
#define ML  (BB*LL)   // 8192 rows

#define NCHUNK 128
#define CHUNK  32     // NCHUNK*CHUNK == LL
#define BDN    (BB*DI*NST)   // 16384

typedef __attribute__((ext_vector_type(8))) short s16x8;
typedef __attribute__((ext_vector_type(4))) float f32x4;

__device__ __forceinline__ ushort f2bf(float f) {
  union { float f; uint32_t u; } v; v.f = f;
  return (ushort)((v.u + 0x7FFFu + ((v.u >> 16) & 1u)) >> 16);  // RNE
}

__device__ __forceinline__ void async16(const void* g, void* l) {
  __builtin_amdgcn_global_load_lds(
      (const __attribute__((address_space(1))) void*)g,
      (__attribute__((address_space(3))) void*)l, 16, 0, 0);
}

// ---------------- generic f32 -> bf16 convert (n4 = count/4) ----------------
__global__ void k_f2b(const float* __restrict__ src, ushort* __restrict__ dst, int n4) {
  int i = blockIdx.x * 256 + threadIdx.x;
  if (i >= n4) return;
  f32x4 v = ((const f32x4*)src)[i];
  *(ushort4*)&dst[i * 4] = make_ushort4(f2bf(v[0]), f2bf(v[1]), f2bf(v[2]), f2bf(v[3]));
}

// ---------------- x_proj_w [48][512] -> padded bf16 [128][512] --------------
__global__ void k_xprojw(const float* __restrict__ src, ushort* __restrict__ dst) {
  int i = blockIdx.x * 256 + threadIdx.x;         // ushort4 groups: 128*512/4
  if (i >= 128 * DI / 4) return;
  int e = i * 4;
  int r = e >> 9;          // /512
  int c = e & 511;
  ushort4 o;
  if (r < DTR + 2 * NST) {
    f32x4 v = *(const f32x4*)&src[r * DI + c];
    o = make_ushort4(f2bf(v[0]), f2bf(v[1]), f2bf(v[2]), f2bf(v[3]));
  } else {
    o = make_ushort4(0, 0, 0, 0);
  }
  *(ushort4*)&dst[e] = o;
}

// ---------------- bf16 MFMA GEMM: out[M][N] = A[M][K] @ W[N][K]^T -----------
template<int OUTF, int OUTB, int BIAS, int RELU>
__global__ __launch_bounds__(256)
void k_gemm(const ushort* __restrict__ A, const ushort* __restrict__ W,
            const float* __restrict__ bias,
            float* __restrict__ outF, ushort* __restrict__ outB,
            int M, int N, int K) {
  __shared__ __align__(16) ushort As[128 * 32];
  __shared__ __align__(16) ushort Bs[128 * 32];
  const int tid  = threadIdx.x;
  const int lane = tid & 63;
  const int wv   = tid >> 6;
  const int m0 = blockIdx.y << 7;
  const int n0 = blockIdx.x << 7;
  const int wr = (wv >> 1) << 6;
  const int wc = (wv & 1) << 6;
  const int lr = lane & 15;
  const int hi = lane >> 4;

  f32x4 acc[4][4] = {};

  const int sr0 = (wv << 5) + (lane >> 2);
  const int sc  = lane & 3;

  for (int k0 = 0; k0 < K; k0 += 32) {
#pragma unroll
    for (int j = 0; j < 2; ++j) {
      const int r  = sr0 + j * 16;
      const int cs = sc ^ (r & 3);
      async16(A + (size_t)(m0 + r) * K + k0 + cs * 8, &As[((wv << 5) + j * 16) * 32]);
      async16(W + (size_t)(n0 + r) * K + k0 + cs * 8, &Bs[((wv << 5) + j * 16) * 32]);
    }
    __syncthreads();

    s16x8 af[4], bf_[4];
#pragma unroll
    for (int mi = 0; mi < 4; ++mi) {
      const int row = wr + mi * 16 + lr;
      af[mi] = *(const s16x8*)&As[row * 32 + ((hi ^ (row & 3)) << 3)];
    }
#pragma unroll
    for (int ni = 0; ni < 4; ++ni) {
      const int row = wc + ni * 16 + lr;
      bf_[ni] = *(const s16x8*)&Bs[row * 32 + ((hi ^ (row & 3)) << 3)];
    }
#pragma unroll
    for (int mi = 0; mi < 4; ++mi)
#pragma unroll
      for (int ni = 0; ni < 4; ++ni)
        acc[mi][ni] = __builtin_amdgcn_mfma_f32_16x16x32_bf16(af[mi], bf_[ni], acc[mi][ni], 0, 0, 0);
    __syncthreads();
  }

#pragma unroll
  for (int mi = 0; mi < 4; ++mi) {
#pragma unroll
    for (int ni = 0; ni < 4; ++ni) {
      const int gc = n0 + wc + ni * 16 + lr;
      const float b = BIAS ? bias[gc] : 0.f;
#pragma unroll
      for (int i = 0; i < 4; ++i) {
        const int gr = m0 + wr + mi * 16 + (hi << 2) + i;
        float v = acc[mi][ni][i] + b;
        if (RELU) v = fmaxf(v, 0.f);
        if (OUTF) outF[(size_t)gr * N + gc] = v;
        if (OUTB) outB[(size_t)gr * N + gc] = f2bf(v);
      }
    }
  }
}

// ---------------- causal depthwise conv (k=4) + SiLU ------------------------
__global__ void k_conv(const float* __restrict__ xz, const float* __restrict__ cw,
                       const float* __restrict__ cb,
                       float* __restrict__ u, ushort* __restrict__ u_bf) {
  const int i = blockIdx.x * 256 + threadIdx.x;    // over ML*DI/4
  if (i >= ML * DI / 4) return;
  const int d4 = i & (DI / 4 - 1);
  const int bl = i / (DI / 4);
  const int l  = bl & (LL - 1);
  const int d  = d4 << 2;
  f32x4 acc;
  acc[0] = cb[d]; acc[1] = cb[d + 1]; acc[2] = cb[d + 2]; acc[3] = cb[d + 3];
#pragma unroll
  for (int j = 0; j < 4; ++j) {
    const int lj = l - 3 + j;
    if (lj >= 0) {
      const f32x4 xv = *(const f32x4*)&xz[(size_t)(bl + j - 3) * 1024 + d];
      acc[0] += xv[0] * cw[(d + 0) * 4 + j];
      acc[1] += xv[1] * cw[(d + 1) * 4 + j];
      acc[2] += xv[2] * cw[(d + 2) * 4 + j];
      acc[3] += xv[3] * cw[(d + 3) * 4 + j];
    }
  }
  f32x4 o;
#pragma unroll
  for (int c = 0; c < 4; ++c) o[c] = acc[c] / (1.f + __expf(-acc[c]));
  *(f32x4*)&u[(size_t)bl * DI + d] = o;
  *(ushort4*)&u_bf[(size_t)bl * DI + d] =
      make_ushort4(f2bf(o[0]), f2bf(o[1]), f2bf(o[2]), f2bf(o[3]));
}

// ---------------- delta = softplus(dt @ dt_proj_w^T + b), K=16 --------------
__global__ void k_dtproj(const float* __restrict__ xdbl, const float* __restrict__ w,
                         const float* __restrict__ bias, float* __restrict__ delta) {
  const int m = blockIdx.x;
  const int tid = threadIdx.x;
  __shared__ float sdt[16];
  if (tid < 16) sdt[tid] = xdbl[(size_t)m * 128 + tid];
  __syncthreads();
#pragma unroll
  for (int rep = 0; rep < 2; ++rep) {
    const int nn = tid + rep * 256;
    float acc = bias[nn];
#pragma unroll
    for (int k = 0; k < 16; ++k) acc += sdt[k] * w[nn * 16 + k];
    delta[(size_t)m * DI + nn] = (acc > 15.f) ? acc : log1pf(__expf(acc));
  }
}

// ======================= chunked parallel selective scan ====================
// Pass 1: per chunk of 32 steps, per (b,d): local scan from h=0 tracking
//   P[n] = prod(dA), S[n] = local state. One thread per d, 16 states in regs.
__global__ __launch_bounds__(256)
void k_scan1(const float* __restrict__ delta, const float* __restrict__ u,
             const float* __restrict__ xdbl, const float* __restrict__ A_log,
             float* __restrict__ Pw, float* __restrict__ Sw) {
  const int c = blockIdx.x;
  const int b = blockIdx.y >> 1;
  const int d = ((blockIdx.y & 1) << 8) + threadIdx.x;
  __shared__ float sB[CHUNK][16];
  {
    const int i = threadIdx.x * 2;            // 512 floats
    const int t = i >> 4, n = i & 15;
    const size_t g = ((size_t)b * LL + (size_t)c * CHUNK + t) * 128 + DTR + n;
    *(float2*)&sB[t][n] = *(const float2*)&xdbl[g];
  }
  float An[16];
#pragma unroll
  for (int j = 0; j < 4; ++j) {
    f32x4 a = *(const f32x4*)&A_log[d * 16 + j * 4];
#pragma unroll
    for (int q = 0; q < 4; ++q) An[j * 4 + q] = -__expf(a[q]);
  }
  float P[16], S[16];
#pragma unroll
  for (int n = 0; n < 16; ++n) { P[n] = 1.f; S[n] = 0.f; }
  __syncthreads();

  const size_t rowbase = ((size_t)b * LL + (size_t)c * CHUNK) * DI + d;
  float dt = delta[rowbase];
  float ut = u[rowbase];
  for (int t = 0; t < CHUNK; ++t) {
    float dt_n = 0.f, ut_n = 0.f;
    if (t + 1 < CHUNK) {
      dt_n = delta[rowbase + (size_t)(t + 1) * DI];
      ut_n = u[rowbase + (size_t)(t + 1) * DI];
    }
    const float k = dt * ut;
#pragma unroll
    for (int n = 0; n < 16; ++n) {
      const float dA = __expf(dt * An[n]);
      S[n] = fmaf(dA, S[n], k * sB[t][n]);
      P[n] *= dA;
    }
    dt = dt_n; ut = ut_n;
  }
  float* Pp = Pw + ((size_t)c * BDN) + ((size_t)b * DI + d) * 16;
  float* Sp = Sw + ((size_t)c * BDN) + ((size_t)b * DI + d) * 16;
#pragma unroll
  for (int j = 0; j < 4; ++j) {
    f32x4 pv, sv;
#pragma unroll
    for (int q = 0; q < 4; ++q) { pv[q] = P[j * 4 + q]; sv[q] = S[j * 4 + q]; }
    *(f32x4*)&Pp[j * 4] = pv;
    *(f32x4*)&Sp[j * 4] = sv;
  }
}

// Pass 2: inter-chunk scan over NCHUNK summaries per (b,d,n).
// Writes chunk start-state Hstart[c] IN PLACE over Pw (read-then-overwrite).
__global__ void k_scan2(float* __restrict__ Pw, const float* __restrict__ Sw) {
  const int f = blockIdx.x * 256 + threadIdx.x;   // [0, BDN)
  float h = 0.f;
#pragma unroll 4
  for (int c = 0; c < NCHUNK; ++c) {
    const float Pc = Pw[(size_t)c * BDN + f];
    const float Sc = Sw[(size_t)c * BDN + f];
    Pw[(size_t)c * BDN + f] = h;
    h = fmaf(Pc, h, Sc);
  }
}

// Pass 3: replay each chunk from Hstart; y = sum_n h*C (in-register), fused
// with +u*D, silu(z) gate, bf16 store.
__global__ __launch_bounds__(256)
void k_scan3(const float* __restrict__ delta, const float* __restrict__ u,
             const float* __restrict__ xdbl, const float* __restrict__ xz,
             const float* __restrict__ A_log, const float* __restrict__ Dp,
             const float* __restrict__ Hs, ushort* __restrict__ y_bf) {
  const int c = blockIdx.x;
  const int b = blockIdx.y >> 1;
  const int d = ((blockIdx.y & 1) << 8) + threadIdx.x;
  __shared__ float sB[CHUNK][16], sC[CHUNK][16];
  {
    const int i = threadIdx.x * 2;
    const int t = i >> 4, n = i & 15;
    const size_t g = ((size_t)b * LL + (size_t)c * CHUNK + t) * 128 + DTR + n;
    *(float2*)&sB[t][n] = *(const float2*)&xdbl[g];
    *(float2*)&sC[t][n] = *(const float2*)&xdbl[g + NST];
  }
  float An[16];
#pragma unroll
  for (int j = 0; j < 4; ++j) {
    f32x4 a = *(const f32x4*)&A_log[d * 16 + j * 4];
#pragma unroll
    for (int q = 0; q < 4; ++q) An[j * 4 + q] = -__expf(a[q]);
  }
  float h[16];
  {
    const float* Hp = Hs + ((size_t)c * BDN) + ((size_t)b * DI + d) * 16;
#pragma unroll
    for (int j = 0; j < 4; ++j) {
      f32x4 v = *(const f32x4*)&Hp[j * 4];
#pragma unroll
      for (int q = 0; q < 4; ++q) h[j * 4 + q] = v[q];
    }
  }
  const float Dd = Dp[d];
  __syncthreads();

  const size_t rowbase = ((size_t)b * LL + (size_t)c * CHUNK) * DI + d;
  const size_t zbase   = ((size_t)b * LL + (size_t)c * CHUNK) * 1024 + DI + d;
  float dt = delta[rowbase];
  float ut = u[rowbase];
  float zt = xz[zbase];
  for (int t = 0; t < CHUNK; ++t) {
    float dt_n = 0.f, ut_n = 0.f, zt_n = 0.f;
    if (t + 1 < CHUNK) {
      dt_n = delta[rowbase + (size_t)(t + 1) * DI];
      ut_n = u[rowbase + (size_t)(t + 1) * DI];
      zt_n = xz[zbase + (size_t)(t + 1) * 1024];
    }
    const float k = dt * ut;
    float y = 0.f;
#pragma unroll
    for (int n = 0; n < 16; ++n) {
      const float dA = __expf(dt * An[n]);
      h[n] = fmaf(dA, h[n], k * sB[t][n]);
      y = fmaf(h[n], sC[t][n], y);
    }
    y = (y + ut * Dd) * (zt / (1.f + __expf(-zt)));
    y_bf[rowbase + (size_t)t * DI] = f2bf(y);
    dt = dt_n; ut = ut_n; zt = zt_n;
  }
}

// ---------------------------------------------------------------------------
extern "C" void kernel_launch(void* const* d_in, const int* in_sizes, int n_in,
                              void* d_out, int out_size, void* d_ws, size_t ws_size,
                              hipStream_t stream) {
  const float* x          = (const float*)d_in[0];
  const float* in_proj_w  = (const float*)d_in[1];
  const float* conv_w     = (const float*)d_in[2];
  const float* conv_b     = (const float*)d_in[3];
  const float* x_proj_w   = (const float*)d_in[4];
  const float* dt_proj_w  = (const float*)d_in[5];
  const float* dt_proj_b  = (const float*)d_in[6];
  const float* A_log      = (const float*)d_in[7];
  const float* Dp         = (const float*)d_in[8];
  const float* out_proj_w = (const float*)d_in[9];
  const float* lin1_w     = (const float*)d_in[10];
  const float* lin1_b     = (const float*)d_in[11];
  const float* lin2_w     = (const float*)d_in[12];
  const float* lin2_b     = (const float*)d_in[13];
  float* out = (float*)d_out;

  char* p = (char*)d_ws;
  auto carve = [&](size_t bytes) -> char* {
    char* r = p;
    p += (bytes + 255) & ~(size_t)255;
    return r;
  };
  ushort* x_bf   = (ushort*)carve((size_t)ML * DM * 2);
  ushort* wip_bf = (ushort*)carve((size_t)2 * DI * DM * 2);
  float*  xz     = (float*) carve((size_t)ML * 1024 * 4);
  float*  u      = (float*) carve((size_t)ML * DI * 4);
  ushort* u_bf   = (ushort*)carve((size_t)ML * DI * 2);
  ushort* xpw_bf = (ushort*)carve((size_t)128 * DI * 2);
  float*  xdbl   = (float*) carve((size_t)ML * 128 * 4);
  float*  delta  = (float*) carve((size_t)ML * DI * 4);
  ushort* y_bf   = (ushort*)carve((size_t)ML * DI * 2);
  ushort* opw_bf = (ushort*)carve((size_t)DM * DI * 2);
  float*  Pws    = (float*) carve((size_t)NCHUNK * BDN * 4);   // 8 MB (then Hstart)
  float*  Sws    = (float*) carve((size_t)NCHUNK * BDN * 4);   // 8 MB
  // lifetime-disjoint aliases (all writes happen after the donor's last read):
  ushort* m_bf   = u_bf;            // u_bf last read by x_proj gemm
  ushort* h1_bf  = (ushort*)xz;     // xz last read by scan3 (z)
  ushort* l1w_bf = (ushort*)delta;  // delta last read by scan3
  ushort* l2w_bf = (ushort*)u;      // u last read by scan3

  // 1) convert x and in_proj_w to bf16
  k_f2b<<<(ML * DM / 4 + 255) / 256, 256, 0, stream>>>(x, x_bf, ML * DM / 4);
  k_f2b<<<(2 * DI * DM / 4 + 255) / 256, 256, 0, stream>>>(in_proj_w, wip_bf, 2 * DI * DM / 4);
  // 2) xz = x @ in_proj_w^T   (M=8192, N=1024, K=256)  -> f32
  k_gemm<1, 0, 0, 0><<<dim3(1024 / 128, ML / 128), 256, 0, stream>>>(
      x_bf, wip_bf, nullptr, xz, nullptr, ML, 1024, DM);
  // 3) causal conv + SiLU -> u (f32 + bf16)
  k_conv<<<(ML * DI / 4 + 255) / 256, 256, 0, stream>>>(xz, conv_w, conv_b, u, u_bf);
  // 4) x_dbl = u @ x_proj_w^T (N padded 48->128, zero rows)  -> f32
  k_xprojw<<<(128 * DI / 4 + 255) / 256, 256, 0, stream>>>(x_proj_w, xpw_bf);
  k_gemm<1, 0, 0, 0><<<dim3(1, ML / 128), 256, 0, stream>>>(
      u_bf, xpw_bf, nullptr, xdbl, nullptr, ML, 128, DI);
  // 5) delta = softplus(dt @ dt_proj_w^T + b)
  k_dtproj<<<ML, 256, 0, stream>>>(xdbl, dt_proj_w, dt_proj_b, delta);
  // 6) chunked selective scan + gating -> y_bf
  k_scan1<<<dim3(NCHUNK, BB * 2), 256, 0, stream>>>(delta, u, xdbl, A_log, Pws, Sws);
  k_scan2<<<BDN / 256, 256, 0, stream>>>(Pws, Sws);
  k_scan3<<<dim3(NCHUNK, BB * 2), 256, 0, stream>>>(delta, u, xdbl, xz, A_log, Dp,
                                                    Pws, y_bf);
  // 7) m = y @ out_proj_w^T (N=256, K=512) -> bf16
  k_f2b<<<(DM * DI / 4 + 255) / 256, 256, 0, stream>>>(out_proj_w, opw_bf, DM * DI / 4);
  k_gemm<0, 1, 0, 0><<<dim3(DM / 128, ML / 128), 256, 0, stream>>>(
      y_bf, opw_bf, nullptr, nullptr, m_bf, ML, DM, DI);
  // 8) h1 = relu(m @ lin1_w^T + b1) (N=2048, K=256) -> bf16
  k_f2b<<<(DFF * DM / 4 + 255) / 256, 256, 0, stream>>>(lin1_w, l1w_bf, DFF * DM / 4);
  k_gemm<0, 1, 1, 1><<<dim3(DFF / 128, ML / 128), 256, 0, stream>>>(
      m_bf, l1w_bf, lin1_b, nullptr, h1_bf, ML, DFF, DM);
  // 9) out = h1 @ lin2_w^T + b2 (N=2048, K=2048) -> f32 to d_out
  k_f2b<<<(DFF * DFF / 4 + 255) / 256, 256, 0, stream>>>(lin2_w, l2w_bf, DFF * DFF / 4);
  k_gemm<1, 0, 1, 0><<<dim3(DFF / 128, ML / 128), 256, 0, stream>>>(
      h1_bf, l2w_bf, lin2_b, out, nullptr, ML, DFF, DFF);
}

// Round 5
// 378.325 us; speedup vs baseline: 3.6119x; 1.0390x over previous
//
#include <hip/hip_runtime.h>
#include <hip/hip_bf16.h>
#include <stdint.h>

#define BB  2
#define LL  4096
#define DM  256
#define DI  512
#define NST 16
#define DTR 16
#define DFF 2048
#define ML  (BB*LL)   // 8192 rows

#define NCHUNK 128
#define CHUNK  32     // NCHUNK*CHUNK == LL
#define BDN    (BB*DI*NST)   // 16384

typedef __attribute__((ext_vector_type(8))) short s16x8;
typedef __attribute__((ext_vector_type(4))) float f32x4;

__device__ __forceinline__ ushort f2bf(float f) {
  union { float f; uint32_t u; } v; v.f = f;
  return (ushort)((v.u + 0x7FFFu + ((v.u >> 16) & 1u)) >> 16);  // RNE
}

__device__ __forceinline__ void async16(const void* g, void* l) {
  __builtin_amdgcn_global_load_lds(
      (const __attribute__((address_space(1))) void*)g,
      (__attribute__((address_space(3))) void*)l, 16, 0, 0);
}

// ---------------- generic f32 -> bf16 convert (n4 = count/4) ----------------
__global__ void k_f2b(const float* __restrict__ src, ushort* __restrict__ dst, int n4) {
  int i = blockIdx.x * 256 + threadIdx.x;
  if (i >= n4) return;
  f32x4 v = ((const f32x4*)src)[i];
  *(ushort4*)&dst[i * 4] = make_ushort4(f2bf(v[0]), f2bf(v[1]), f2bf(v[2]), f2bf(v[3]));
}

// ---------------- x_proj_w [48][512] -> padded bf16 [128][512] --------------
__global__ void k_xprojw(const float* __restrict__ src, ushort* __restrict__ dst) {
  int i = blockIdx.x * 256 + threadIdx.x;         // ushort4 groups: 128*512/4
  if (i >= 128 * DI / 4) return;
  int e = i * 4;
  int r = e >> 9;          // /512
  int c = e & 511;
  ushort4 o;
  if (r < DTR + 2 * NST) {
    f32x4 v = *(const f32x4*)&src[r * DI + c];
    o = make_ushort4(f2bf(v[0]), f2bf(v[1]), f2bf(v[2]), f2bf(v[3]));
  } else {
    o = make_ushort4(0, 0, 0, 0);
  }
  *(ushort4*)&dst[e] = o;
}

// ---------------- bf16 MFMA GEMM: out[M][N] = A[M][K] @ W[N][K]^T -----------
// 128x128 tile, 4 waves (2x2, 64x64 each), BK=32.
// 3-buffer LDS pipeline with counted vmcnt(4): stage tile t+2 while computing
// tile t; one barrier per K-step; loads stay in flight across barriers (T4).
// Swizzle s(r)=(r>>1)&3 on the 16B chunk: ds_read_b128 lands at exactly 2
// lanes/bank (free). XCD-aware block swizzle (grids are %8==0).
template<int OUTF, int OUTB, int BIAS, int RELU>
__global__ __launch_bounds__(256)
void k_gemm(const ushort* __restrict__ A, const ushort* __restrict__ W,
            const float* __restrict__ bias,
            float* __restrict__ outF, ushort* __restrict__ outB,
            int M, int N, int K) {
  __shared__ __align__(16) ushort AsB[3][128 * 32];
  __shared__ __align__(16) ushort BsB[3][128 * 32];
  const int tid  = threadIdx.x;
  const int lane = tid & 63;
  const int wv   = tid >> 6;

  // XCD-aware bijective swizzle of the flat block id (nwg % 8 == 0 for all grids here)
  const int nwg  = gridDim.x * gridDim.y;
  const int flat = blockIdx.y * gridDim.x + blockIdx.x;
  const int cpx  = nwg >> 3;
  const int swz  = (flat & 7) * cpx + (flat >> 3);
  const int m0 = (swz / gridDim.x) << 7;
  const int n0 = (swz % gridDim.x) << 7;

  const int wr = (wv >> 1) << 6;
  const int wc = (wv & 1) << 6;
  const int lr = lane & 15;
  const int hi = lane >> 4;

  f32x4 acc[4][4] = {};

  const int sr0 = (wv << 5) + (lane >> 2);   // staging row in tile (this wave: wv*32..+31)
  const int sc  = lane & 3;                  // linear 16B-chunk slot in LDS

  const int nt = K >> 5;                     // K/32 tiles (all K here are >=128)

  auto STAGE = [&](int t, int bi) {
    const int k0 = t << 5;
#pragma unroll
    for (int j = 0; j < 2; ++j) {
      const int r  = sr0 + j * 16;
      const int cs = sc ^ ((r >> 1) & 3);    // pre-swizzled global source chunk
      async16(A + (size_t)(m0 + r) * K + k0 + cs * 8, &AsB[bi][((wv << 5) + j * 16) * 32]);
      async16(W + (size_t)(n0 + r) * K + k0 + cs * 8, &BsB[bi][((wv << 5) + j * 16) * 32]);
    }
  };

  STAGE(0, 0);
  STAGE(1, 1);

  int cur = 0;
  for (int t = 0; t < nt; ++t) {
    // wait for tile t's staging (4 loads/wave of tile t+1 may stay in flight)
    if (t + 1 < nt) { asm volatile("s_waitcnt vmcnt(4)" ::: "memory"); }
    else            { asm volatile("s_waitcnt vmcnt(0)" ::: "memory"); }
    __builtin_amdgcn_s_barrier();
    __builtin_amdgcn_sched_barrier(0);

    if (t + 2 < nt) {
      int nx2 = cur + 2; if (nx2 >= 3) nx2 -= 3;
      STAGE(t + 2, nx2);
    }

    const ushort* As = AsB[cur];
    const ushort* Bs = BsB[cur];
    s16x8 af[4], bf_[4];
#pragma unroll
    for (int mi = 0; mi < 4; ++mi) {
      const int row = wr + mi * 16 + lr;
      af[mi] = *(const s16x8*)&As[row * 32 + ((hi ^ ((row >> 1) & 3)) << 3)];
    }
#pragma unroll
    for (int ni = 0; ni < 4; ++ni) {
      const int row = wc + ni * 16 + lr;
      bf_[ni] = *(const s16x8*)&Bs[row * 32 + ((hi ^ ((row >> 1) & 3)) << 3)];
    }
    asm volatile("s_waitcnt lgkmcnt(0)" ::: "memory");
    __builtin_amdgcn_sched_barrier(0);

    __builtin_amdgcn_s_setprio(1);
#pragma unroll
    for (int mi = 0; mi < 4; ++mi)
#pragma unroll
      for (int ni = 0; ni < 4; ++ni)
        acc[mi][ni] = __builtin_amdgcn_mfma_f32_16x16x32_bf16(af[mi], bf_[ni], acc[mi][ni], 0, 0, 0);
    __builtin_amdgcn_s_setprio(0);

    cur = (cur + 1 == 3) ? 0 : cur + 1;
  }

#pragma unroll
  for (int mi = 0; mi < 4; ++mi) {
#pragma unroll
    for (int ni = 0; ni < 4; ++ni) {
      const int gc = n0 + wc + ni * 16 + lr;           // C/D: col = lane&15
      const float b = BIAS ? bias[gc] : 0.f;
#pragma unroll
      for (int i = 0; i < 4; ++i) {
        const int gr = m0 + wr + mi * 16 + (hi << 2) + i;  // row = (lane>>4)*4+reg
        float v = acc[mi][ni][i] + b;
        if (RELU) v = fmaxf(v, 0.f);
        if (OUTF) outF[(size_t)gr * N + gc] = v;
        if (OUTB) outB[(size_t)gr * N + gc] = f2bf(v);
      }
    }
  }
}

// ---------------- causal depthwise conv (k=4) + SiLU ------------------------
__global__ void k_conv(const float* __restrict__ xz, const float* __restrict__ cw,
                       const float* __restrict__ cb,
                       float* __restrict__ u, ushort* __restrict__ u_bf) {
  const int i = blockIdx.x * 256 + threadIdx.x;    // over ML*DI/4
  if (i >= ML * DI / 4) return;
  const int d4 = i & (DI / 4 - 1);
  const int bl = i / (DI / 4);
  const int l  = bl & (LL - 1);
  const int d  = d4 << 2;
  f32x4 acc;
  acc[0] = cb[d]; acc[1] = cb[d + 1]; acc[2] = cb[d + 2]; acc[3] = cb[d + 3];
#pragma unroll
  for (int j = 0; j < 4; ++j) {
    const int lj = l - 3 + j;
    if (lj >= 0) {
      const f32x4 xv = *(const f32x4*)&xz[(size_t)(bl + j - 3) * 1024 + d];
      acc[0] += xv[0] * cw[(d + 0) * 4 + j];
      acc[1] += xv[1] * cw[(d + 1) * 4 + j];
      acc[2] += xv[2] * cw[(d + 2) * 4 + j];
      acc[3] += xv[3] * cw[(d + 3) * 4 + j];
    }
  }
  f32x4 o;
#pragma unroll
  for (int c = 0; c < 4; ++c) o[c] = acc[c] / (1.f + __expf(-acc[c]));
  *(f32x4*)&u[(size_t)bl * DI + d] = o;
  *(ushort4*)&u_bf[(size_t)bl * DI + d] =
      make_ushort4(f2bf(o[0]), f2bf(o[1]), f2bf(o[2]), f2bf(o[3]));
}

// ======================= chunked parallel selective scan ====================
// delta = softplus(dt_row @ dt_proj_w^T + b) is computed INLINE in both scan
// passes (identical code -> identical values); the delta buffer + k_dtproj
// kernel are gone (saves 48 MB of HBM traffic + a launch).
// Pass 1: per chunk of 32 steps, per (b,d): local scan from h=0 tracking
//   P[n] = prod(dA), S[n] = local state. One thread per d, 16 states in regs.
__global__ __launch_bounds__(256)
void k_scan1(const float* __restrict__ u, const float* __restrict__ xdbl,
             const float* __restrict__ A_log, const float* __restrict__ dtw,
             const float* __restrict__ dtb,
             float* __restrict__ Pw, float* __restrict__ Sw) {
  const int c = blockIdx.x;
  const int b = blockIdx.y >> 1;
  const int d = ((blockIdx.y & 1) << 8) + threadIdx.x;
  __shared__ float sdt[CHUNK][16], sB[CHUNK][16];
  {
    const int i = threadIdx.x * 2;            // 512 floats each
    const int t = i >> 4, n = i & 15;
    const size_t g = ((size_t)b * LL + (size_t)c * CHUNK + t) * 128 + n;
    *(float2*)&sdt[t][n] = *(const float2*)&xdbl[g];
    *(float2*)&sB[t][n]  = *(const float2*)&xdbl[g + DTR];
  }
  float An[16], wreg[16];
#pragma unroll
  for (int j = 0; j < 4; ++j) {
    f32x4 a = *(const f32x4*)&A_log[d * 16 + j * 4];
    f32x4 w = *(const f32x4*)&dtw[d * 16 + j * 4];
#pragma unroll
    for (int q = 0; q < 4; ++q) { An[j * 4 + q] = -__expf(a[q]); wreg[j * 4 + q] = w[q]; }
  }
  const float bd = dtb[d];
  float P[16], S[16];
#pragma unroll
  for (int n = 0; n < 16; ++n) { P[n] = 1.f; S[n] = 0.f; }
  __syncthreads();

  const size_t rowbase = ((size_t)b * LL + (size_t)c * CHUNK) * DI + d;
  float ut = u[rowbase];
  for (int t = 0; t < CHUNK; ++t) {
    const float ut_n = (t + 1 < CHUNK) ? u[rowbase + (size_t)(t + 1) * DI] : 0.f;
    float a = bd;
#pragma unroll
    for (int k2 = 0; k2 < 16; ++k2) a = fmaf(sdt[t][k2], wreg[k2], a);
    const float dt = (a > 15.f) ? a : log1pf(__expf(a));
    const float k = dt * ut;
#pragma unroll
    for (int n = 0; n < 16; ++n) {
      const float dA = __expf(dt * An[n]);
      S[n] = fmaf(dA, S[n], k * sB[t][n]);
      P[n] *= dA;
    }
    ut = ut_n;
  }
  float* Pp = Pw + ((size_t)c * BDN) + ((size_t)b * DI + d) * 16;
  float* Sp = Sw + ((size_t)c * BDN) + ((size_t)b * DI + d) * 16;
#pragma unroll
  for (int j = 0; j < 4; ++j) {
    f32x4 pv, sv;
#pragma unroll
    for (int q = 0; q < 4; ++q) { pv[q] = P[j * 4 + q]; sv[q] = S[j * 4 + q]; }
    *(f32x4*)&Pp[j * 4] = pv;
    *(f32x4*)&Sp[j * 4] = sv;
  }
}

// Pass 2: inter-chunk scan over NCHUNK summaries per (b,d,n).
// Writes chunk start-state Hstart[c] IN PLACE over Pw (read-then-overwrite).
__global__ void k_scan2(float* __restrict__ Pw, const float* __restrict__ Sw) {
  const int f = blockIdx.x * 256 + threadIdx.x;   // [0, BDN)
  float h = 0.f;
#pragma unroll 4
  for (int c = 0; c < NCHUNK; ++c) {
    const float Pc = Pw[(size_t)c * BDN + f];
    const float Sc = Sw[(size_t)c * BDN + f];
    Pw[(size_t)c * BDN + f] = h;
    h = fmaf(Pc, h, Sc);
  }
}

// Pass 3: replay each chunk from Hstart; y = sum_n h*C (in-register), fused
// with +u*D, silu(z) gate, bf16 store.
__global__ __launch_bounds__(256)
void k_scan3(const float* __restrict__ u, const float* __restrict__ xdbl,
             const float* __restrict__ xz, const float* __restrict__ A_log,
             const float* __restrict__ dtw, const float* __restrict__ dtb,
             const float* __restrict__ Dp,
             const float* __restrict__ Hs, ushort* __restrict__ y_bf) {
  const int c = blockIdx.x;
  const int b = blockIdx.y >> 1;
  const int d = ((blockIdx.y & 1) << 8) + threadIdx.x;
  __shared__ float sdt[CHUNK][16], sB[CHUNK][16], sC[CHUNK][16];
  {
    const int i = threadIdx.x * 2;
    const int t = i >> 4, n = i & 15;
    const size_t g = ((size_t)b * LL + (size_t)c * CHUNK + t) * 128 + n;
    *(float2*)&sdt[t][n] = *(const float2*)&xdbl[g];
    *(float2*)&sB[t][n]  = *(const float2*)&xdbl[g + DTR];
    *(float2*)&sC[t][n]  = *(const float2*)&xdbl[g + DTR + NST];
  }
  float An[16], wreg[16];
#pragma unroll
  for (int j = 0; j < 4; ++j) {
    f32x4 a = *(const f32x4*)&A_log[d * 16 + j * 4];
    f32x4 w = *(const f32x4*)&dtw[d * 16 + j * 4];
#pragma unroll
    for (int q = 0; q < 4; ++q) { An[j * 4 + q] = -__expf(a[q]); wreg[j * 4 + q] = w[q]; }
  }
  const float bd = dtb[d];
  float h[16];
  {
    const float* Hp = Hs + ((size_t)c * BDN) + ((size_t)b * DI + d) * 16;
#pragma unroll
    for (int j = 0; j < 4; ++j) {
      f32x4 v = *(const f32x4*)&Hp[j * 4];
#pragma unroll
      for (int q = 0; q < 4; ++q) h[j * 4 + q] = v[q];
    }
  }
  const float Dd = Dp[d];
  __syncthreads();

  const size_t rowbase = ((size_t)b * LL + (size_t)c * CHUNK) * DI + d;
  const size_t zbase   = ((size_t)b * LL + (size_t)c * CHUNK) * 1024 + DI + d;
  float ut = u[rowbase];
  float zt = xz[zbase];
  for (int t = 0; t < CHUNK; ++t) {
    float ut_n = 0.f, zt_n = 0.f;
    if (t + 1 < CHUNK) {
      ut_n = u[rowbase + (size_t)(t + 1) * DI];
      zt_n = xz[zbase + (size_t)(t + 1) * 1024];
    }
    float a = bd;
#pragma unroll
    for (int k2 = 0; k2 < 16; ++k2) a = fmaf(sdt[t][k2], wreg[k2], a);
    const float dt = (a > 15.f) ? a : log1pf(__expf(a));
    const float k = dt * ut;
    float y = 0.f;
#pragma unroll
    for (int n = 0; n < 16; ++n) {
      const float dA = __expf(dt * An[n]);
      h[n] = fmaf(dA, h[n], k * sB[t][n]);
      y = fmaf(h[n], sC[t][n], y);
    }
    y = (y + ut * Dd) * (zt / (1.f + __expf(-zt)));
    y_bf[rowbase + (size_t)t * DI] = f2bf(y);
    ut = ut_n; zt = zt_n;
  }
}

// ---------------------------------------------------------------------------
extern "C" void kernel_launch(void* const* d_in, const int* in_sizes, int n_in,
                              void* d_out, int out_size, void* d_ws, size_t ws_size,
                              hipStream_t stream) {
  const float* x          = (const float*)d_in[0];
  const float* in_proj_w  = (const float*)d_in[1];
  const float* conv_w     = (const float*)d_in[2];
  const float* conv_b     = (const float*)d_in[3];
  const float* x_proj_w   = (const float*)d_in[4];
  const float* dt_proj_w  = (const float*)d_in[5];
  const float* dt_proj_b  = (const float*)d_in[6];
  const float* A_log      = (const float*)d_in[7];
  const float* Dp         = (const float*)d_in[8];
  const float* out_proj_w = (const float*)d_in[9];
  const float* lin1_w     = (const float*)d_in[10];
  const float* lin1_b     = (const float*)d_in[11];
  const float* lin2_w     = (const float*)d_in[12];
  const float* lin2_b     = (const float*)d_in[13];
  float* out = (float*)d_out;

  char* p = (char*)d_ws;
  auto carve = [&](size_t bytes) -> char* {
    char* r = p;
    p += (bytes + 255) & ~(size_t)255;
    return r;
  };
  ushort* x_bf   = (ushort*)carve((size_t)ML * DM * 2);
  ushort* wip_bf = (ushort*)carve((size_t)2 * DI * DM * 2);
  float*  xz     = (float*) carve((size_t)ML * 1024 * 4);
  float*  u      = (float*) carve((size_t)ML * DI * 4);
  ushort* u_bf   = (ushort*)carve((size_t)ML * DI * 2);
  ushort* xpw_bf = (ushort*)carve((size_t)128 * DI * 2);
  float*  xdbl   = (float*) carve((size_t)ML * 128 * 4);
  ushort* y_bf   = (ushort*)carve((size_t)ML * DI * 2);
  ushort* opw_bf = (ushort*)carve((size_t)DM * DI * 2);
  ushort* l1w_bf = (ushort*)carve((size_t)DFF * DM * 2);
  float*  Pws    = (float*) carve((size_t)NCHUNK * BDN * 4);   // 8 MB (then Hstart)
  float*  Sws    = (float*) carve((size_t)NCHUNK * BDN * 4);   // 8 MB
  // lifetime-disjoint aliases (all writes happen after the donor's last read):
  ushort* m_bf   = u_bf;            // u_bf last read by x_proj gemm
  ushort* h1_bf  = (ushort*)xz;     // xz last read by scan3 (z)
  ushort* l2w_bf = (ushort*)u;      // u last read by scan3

  // 1) convert x and in_proj_w to bf16
  k_f2b<<<(ML * DM / 4 + 255) / 256, 256, 0, stream>>>(x, x_bf, ML * DM / 4);
  k_f2b<<<(2 * DI * DM / 4 + 255) / 256, 256, 0, stream>>>(in_proj_w, wip_bf, 2 * DI * DM / 4);
  // 2) xz = x @ in_proj_w^T   (M=8192, N=1024, K=256)  -> f32
  k_gemm<1, 0, 0, 0><<<dim3(1024 / 128, ML / 128), 256, 0, stream>>>(
      x_bf, wip_bf, nullptr, xz, nullptr, ML, 1024, DM);
  // 3) causal conv + SiLU -> u (f32 + bf16)
  k_conv<<<(ML * DI / 4 + 255) / 256, 256, 0, stream>>>(xz, conv_w, conv_b, u, u_bf);
  // 4) x_dbl = u @ x_proj_w^T (N padded 48->128, zero rows)  -> f32
  k_xprojw<<<(128 * DI / 4 + 255) / 256, 256, 0, stream>>>(x_proj_w, xpw_bf);
  k_gemm<1, 0, 0, 0><<<dim3(1, ML / 128), 256, 0, stream>>>(
      u_bf, xpw_bf, nullptr, xdbl, nullptr, ML, 128, DI);
  // 5) chunked selective scan (inline softplus(dt-proj)) + gating -> y_bf
  k_scan1<<<dim3(NCHUNK, BB * 2), 256, 0, stream>>>(u, xdbl, A_log, dt_proj_w,
                                                    dt_proj_b, Pws, Sws);
  k_scan2<<<BDN / 256, 256, 0, stream>>>(Pws, Sws);
  k_scan3<<<dim3(NCHUNK, BB * 2), 256, 0, stream>>>(u, xdbl, xz, A_log, dt_proj_w,
                                                    dt_proj_b, Dp, Pws, y_bf);
  // 6) m = y @ out_proj_w^T (N=256, K=512) -> bf16
  k_f2b<<<(DM * DI / 4 + 255) / 256, 256, 0, stream>>>(out_proj_w, opw_bf, DM * DI / 4);
  k_gemm<0, 1, 0, 0><<<dim3(DM / 128, ML / 128), 256, 0, stream>>>(
      y_bf, opw_bf, nullptr, nullptr, m_bf, ML, DM, DI);
  // 7) h1 = relu(m @ lin1_w^T + b1) (N=2048, K=256) -> bf16
  k_f2b<<<(DFF * DM / 4 + 255) / 256, 256, 0, stream>>>(lin1_w, l1w_bf, DFF * DM / 4);
  k_gemm<0, 1, 1, 1><<<dim3(DFF / 128, ML / 128), 256, 0, stream>>>(
      m_bf, l1w_bf, lin1_b, nullptr, h1_bf, ML, DFF, DM);
  // 8) out = h1 @ lin2_w^T + b2 (N=2048, K=2048) -> f32 to d_out
  k_f2b<<<(DFF * DFF / 4 + 255) / 256, 256, 0, stream>>>(lin2_w, l2w_bf, DFF * DFF / 4);
  k_gemm<1, 0, 1, 0><<<dim3(DFF / 128, ML / 128), 256, 0, stream>>>(
      h1_bf, l2w_bf, lin2_b, out, nullptr, ML, DFF, DFF);
}

// Round 7
// 369.493 us; speedup vs baseline: 3.6983x; 1.0239x over previous
//
#include <hip/hip_runtime.h>
#include <hip/hip_bf16.h>
#include <stdint.h>

#define BB  2
#define LL  4096
#define DM  256
#define DI  512
#define NST 16
#define DTR 16
#define DFF 2048
#define ML  (BB*LL)   // 8192 rows

#define NCHUNK 128
#define CHUNK  32     // NCHUNK*CHUNK == LL
#define BDN    (BB*DI*NST)   // 16384

typedef __attribute__((ext_vector_type(8))) short s16x8;
typedef __attribute__((ext_vector_type(4))) float f32x4;

__device__ __forceinline__ ushort f2bf(float f) {
  union { float f; uint32_t u; } v; v.f = f;
  return (ushort)((v.u + 0x7FFFu + ((v.u >> 16) & 1u)) >> 16);  // RNE
}

__device__ __forceinline__ void async16(const void* g, void* l) {
  __builtin_amdgcn_global_load_lds(
      (const __attribute__((address_space(1))) void*)g,
      (__attribute__((address_space(3))) void*)l, 16, 0, 0);
}

// ---------------- generic f32 -> bf16 convert (n4 = count/4) ----------------
__global__ void k_f2b(const float* __restrict__ src, ushort* __restrict__ dst, int n4) {
  int i = blockIdx.x * 256 + threadIdx.x;
  if (i >= n4) return;
  f32x4 v = ((const f32x4*)src)[i];
  *(ushort4*)&dst[i * 4] = make_ushort4(f2bf(v[0]), f2bf(v[1]), f2bf(v[2]), f2bf(v[3]));
}

// ---------------- x_proj_w [48][512] -> padded bf16 [128][512] --------------
__global__ void k_xprojw(const float* __restrict__ src, ushort* __restrict__ dst) {
  int i = blockIdx.x * 256 + threadIdx.x;         // ushort4 groups: 128*512/4
  if (i >= 128 * DI / 4) return;
  int e = i * 4;
  int r = e >> 9;          // /512
  int c = e & 511;
  ushort4 o;
  if (r < DTR + 2 * NST) {
    f32x4 v = *(const f32x4*)&src[r * DI + c];
    o = make_ushort4(f2bf(v[0]), f2bf(v[1]), f2bf(v[2]), f2bf(v[3]));
  } else {
    o = make_ushort4(0, 0, 0, 0);
  }
  *(ushort4*)&dst[e] = o;
}

// ---------------- 128x128 bf16 MFMA GEMM (small-N shapes) -------------------
// 3-buffer LDS pipeline, counted vmcnt(4); swizzle s(r)=(r>>1)&3 (2-way, free).
template<int OUTF, int OUTB, int BIAS, int RELU>
__global__ __launch_bounds__(256)
void k_gemm(const ushort* __restrict__ A, const ushort* __restrict__ W,
            const float* __restrict__ bias,
            float* __restrict__ outF, ushort* __restrict__ outB,
            int M, int N, int K) {
  __shared__ __align__(16) ushort AsB[3][128 * 32];
  __shared__ __align__(16) ushort BsB[3][128 * 32];
  const int tid  = threadIdx.x;
  const int lane = tid & 63;
  const int wv   = tid >> 6;

  const int nwg  = gridDim.x * gridDim.y;
  const int flat = blockIdx.y * gridDim.x + blockIdx.x;
  const int cpx  = nwg >> 3;
  const int swz  = (nwg & 7) ? flat : (flat & 7) * cpx + (flat >> 3);
  const int m0 = (swz / gridDim.x) << 7;
  const int n0 = (swz % gridDim.x) << 7;

  const int wr = (wv >> 1) << 6;
  const int wc = (wv & 1) << 6;
  const int lr = lane & 15;
  const int hi = lane >> 4;

  f32x4 acc[4][4] = {};

  const int sr0 = (wv << 5) + (lane >> 2);
  const int sc  = lane & 3;
  const int nt = K >> 5;

  auto STAGE = [&](int t, int bi) {
    const int k0 = t << 5;
#pragma unroll
    for (int j = 0; j < 2; ++j) {
      const int r  = sr0 + j * 16;
      const int cs = sc ^ ((r >> 1) & 3);
      async16(A + (size_t)(m0 + r) * K + k0 + cs * 8, &AsB[bi][((wv << 5) + j * 16) * 32]);
      async16(W + (size_t)(n0 + r) * K + k0 + cs * 8, &BsB[bi][((wv << 5) + j * 16) * 32]);
    }
  };

  STAGE(0, 0);
  STAGE(1, 1);

  int cur = 0;
  for (int t = 0; t < nt; ++t) {
    if (t + 1 < nt) { asm volatile("s_waitcnt vmcnt(4)" ::: "memory"); }
    else            { asm volatile("s_waitcnt vmcnt(0)" ::: "memory"); }
    __builtin_amdgcn_s_barrier();
    __builtin_amdgcn_sched_barrier(0);

    if (t + 2 < nt) {
      int nx2 = cur + 2; if (nx2 >= 3) nx2 -= 3;
      STAGE(t + 2, nx2);
    }

    const ushort* As = AsB[cur];
    const ushort* Bs = BsB[cur];
    s16x8 af[4], bf_[4];
#pragma unroll
    for (int mi = 0; mi < 4; ++mi) {
      const int row = wr + mi * 16 + lr;
      af[mi] = *(const s16x8*)&As[row * 32 + ((hi ^ ((row >> 1) & 3)) << 3)];
    }
#pragma unroll
    for (int ni = 0; ni < 4; ++ni) {
      const int row = wc + ni * 16 + lr;
      bf_[ni] = *(const s16x8*)&Bs[row * 32 + ((hi ^ ((row >> 1) & 3)) << 3)];
    }
    asm volatile("s_waitcnt lgkmcnt(0)" ::: "memory");
    __builtin_amdgcn_sched_barrier(0);

    __builtin_amdgcn_s_setprio(1);
#pragma unroll
    for (int mi = 0; mi < 4; ++mi)
#pragma unroll
      for (int ni = 0; ni < 4; ++ni)
        acc[mi][ni] = __builtin_amdgcn_mfma_f32_16x16x32_bf16(af[mi], bf_[ni], acc[mi][ni], 0, 0, 0);
    __builtin_amdgcn_s_setprio(0);

    cur = (cur + 1 == 3) ? 0 : cur + 1;
  }

#pragma unroll
  for (int mi = 0; mi < 4; ++mi) {
#pragma unroll
    for (int ni = 0; ni < 4; ++ni) {
      const int gc = n0 + wc + ni * 16 + lr;
      const float b = BIAS ? bias[gc] : 0.f;
#pragma unroll
      for (int i = 0; i < 4; ++i) {
        const int gr = m0 + wr + mi * 16 + (hi << 2) + i;
        float v = acc[mi][ni][i] + b;
        if (RELU) v = fmaxf(v, 0.f);
        if (OUTF) outF[(size_t)gr * N + gc] = v;
        if (OUTB) outB[(size_t)gr * N + gc] = f2bf(v);
      }
    }
  }
}

// ---------------- 256x256 bf16 MFMA GEMM (lin1/lin2, N>=2048) ---------------
// 512 thr = 8 waves (2M x 4N), per-wave 128x64 output, BK=32.
// 4-buffer LDS ring (128 KiB), prefetch depth 3, counted vmcnt(8): tiles
// t+1,t+2 stay in flight across the barrier; t+3 staged after the barrier
// into the buffer freed at t-1 (WAR safe: every wave's lgkmcnt(0) in iter
// t-1 precedes the iter-t barrier). 32 MFMA per 12 ds_read_b128 per wave.
template<int OUTF, int OUTB, int BIAS, int RELU>
__global__ __launch_bounds__(512, 2)
void k_gemm256(const ushort* __restrict__ A, const ushort* __restrict__ W,
               const float* __restrict__ bias,
               float* __restrict__ outF, ushort* __restrict__ outB,
               int M, int N, int K) {
  __shared__ __align__(16) ushort AsB[4][256 * 32];  // 64 KiB
  __shared__ __align__(16) ushort BsB[4][256 * 32];  // 64 KiB
  const int tid  = threadIdx.x;
  const int lane = tid & 63;
  const int wv   = tid >> 6;          // 0..7

  const int nwg  = gridDim.x * gridDim.y;
  const int flat = blockIdx.y * gridDim.x + blockIdx.x;
  const int cpx  = nwg >> 3;
  const int swz  = (nwg & 7) ? flat : (flat & 7) * cpx + (flat >> 3);
  const int m0 = (swz / gridDim.x) << 8;
  const int n0 = (swz % gridDim.x) << 8;

  const int wrM = (wv >> 2) << 7;     // 0 / 128
  const int wcN = (wv & 3) << 6;      // 0 / 64 / 128 / 192
  const int lr = lane & 15;
  const int hi = lane >> 4;

  f32x4 acc[8][4] = {};

  const int sr0 = (wv << 5) + (lane >> 2);   // this wave stages rows wv*32..+31
  const int sc  = lane & 3;
  const int nt  = K >> 5;

  auto STAGE = [&](int t, int bi) {
    const int k0 = t << 5;
#pragma unroll
    for (int j = 0; j < 2; ++j) {
      const int r  = sr0 + j * 16;
      const int cs = sc ^ ((r >> 1) & 3);    // pre-swizzled global source chunk
      async16(A + (size_t)(m0 + r) * K + k0 + cs * 8, &AsB[bi][((wv << 5) + j * 16) * 32]);
      async16(W + (size_t)(n0 + r) * K + k0 + cs * 8, &BsB[bi][((wv << 5) + j * 16) * 32]);
    }
  };

  STAGE(0, 0);
  STAGE(1, 1);
  STAGE(2, 2);

  int cur = 0;
  for (int t = 0; t < nt; ++t) {
    const int fly = nt - 1 - t;        // staged tiles beyond t at this point
    if (fly >= 2)      { asm volatile("s_waitcnt vmcnt(8)" ::: "memory"); }
    else if (fly == 1) { asm volatile("s_waitcnt vmcnt(4)" ::: "memory"); }
    else               { asm volatile("s_waitcnt vmcnt(0)" ::: "memory"); }
    __builtin_amdgcn_s_barrier();
    __builtin_amdgcn_sched_barrier(0);

    if (t + 3 < nt) STAGE(t + 3, (cur + 3) & 3);

    const ushort* As = AsB[cur];
    const ushort* Bs = BsB[cur];
    s16x8 bf_[4], af[8];
#pragma unroll
    for (int ni = 0; ni < 4; ++ni) {
      const int row = wcN + ni * 16 + lr;
      bf_[ni] = *(const s16x8*)&Bs[row * 32 + ((hi ^ ((row >> 1) & 3)) << 3)];
    }
#pragma unroll
    for (int mi = 0; mi < 8; ++mi) {
      const int row = wrM + mi * 16 + lr;
      af[mi] = *(const s16x8*)&As[row * 32 + ((hi ^ ((row >> 1) & 3)) << 3)];
    }
    asm volatile("s_waitcnt lgkmcnt(0)" ::: "memory");
    __builtin_amdgcn_sched_barrier(0);

    __builtin_amdgcn_s_setprio(1);
#pragma unroll
    for (int mi = 0; mi < 8; ++mi)
#pragma unroll
      for (int ni = 0; ni < 4; ++ni)
        acc[mi][ni] = __builtin_amdgcn_mfma_f32_16x16x32_bf16(af[mi], bf_[ni], acc[mi][ni], 0, 0, 0);
    __builtin_amdgcn_s_setprio(0);

    cur = (cur + 1) & 3;
  }

#pragma unroll
  for (int mi = 0; mi < 8; ++mi) {
#pragma unroll
    for (int ni = 0; ni < 4; ++ni) {
      const int gc = n0 + wcN + ni * 16 + lr;
      const float b = BIAS ? bias[gc] : 0.f;
#pragma unroll
      for (int i = 0; i < 4; ++i) {
        const int gr = m0 + wrM + mi * 16 + (hi << 2) + i;
        float v = acc[mi][ni][i] + b;
        if (RELU) v = fmaxf(v, 0.f);
        if (OUTF) outF[(size_t)gr * N + gc] = v;
        if (OUTB) outB[(size_t)gr * N + gc] = f2bf(v);
      }
    }
  }
}

// ---------------- causal depthwise conv (k=4) + SiLU ------------------------
__global__ void k_conv(const float* __restrict__ xz, const float* __restrict__ cw,
                       const float* __restrict__ cb,
                       float* __restrict__ u, ushort* __restrict__ u_bf) {
  const int i = blockIdx.x * 256 + threadIdx.x;    // over ML*DI/4
  if (i >= ML * DI / 4) return;
  const int d4 = i & (DI / 4 - 1);
  const int bl = i / (DI / 4);
  const int l  = bl & (LL - 1);
  const int d  = d4 << 2;
  f32x4 acc;
  acc[0] = cb[d]; acc[1] = cb[d + 1]; acc[2] = cb[d + 2]; acc[3] = cb[d + 3];
#pragma unroll
  for (int j = 0; j < 4; ++j) {
    const int lj = l - 3 + j;
    if (lj >= 0) {
      const f32x4 xv = *(const f32x4*)&xz[(size_t)(bl + j - 3) * 1024 + d];
      acc[0] += xv[0] * cw[(d + 0) * 4 + j];
      acc[1] += xv[1] * cw[(d + 1) * 4 + j];
      acc[2] += xv[2] * cw[(d + 2) * 4 + j];
      acc[3] += xv[3] * cw[(d + 3) * 4 + j];
    }
  }
  f32x4 o;
#pragma unroll
  for (int c = 0; c < 4; ++c) o[c] = acc[c] / (1.f + __expf(-acc[c]));
  *(f32x4*)&u[(size_t)bl * DI + d] = o;
  *(ushort4*)&u_bf[(size_t)bl * DI + d] =
      make_ushort4(f2bf(o[0]), f2bf(o[1]), f2bf(o[2]), f2bf(o[3]));
}

// ======================= chunked parallel selective scan ====================
// delta = softplus(dt_row @ dt_proj_w^T + b) computed INLINE in both passes.
__global__ __launch_bounds__(256)
void k_scan1(const float* __restrict__ u, const float* __restrict__ xdbl,
             const float* __restrict__ A_log, const float* __restrict__ dtw,
             const float* __restrict__ dtb,
             float* __restrict__ Pw, float* __restrict__ Sw) {
  const int c = blockIdx.x;
  const int b = blockIdx.y >> 1;
  const int d = ((blockIdx.y & 1) << 8) + threadIdx.x;
  __shared__ float sdt[CHUNK][16], sB[CHUNK][16];
  {
    const int i = threadIdx.x * 2;            // 512 floats each
    const int t = i >> 4, n = i & 15;
    const size_t g = ((size_t)b * LL + (size_t)c * CHUNK + t) * 128 + n;
    *(float2*)&sdt[t][n] = *(const float2*)&xdbl[g];
    *(float2*)&sB[t][n]  = *(const float2*)&xdbl[g + DTR];
  }
  float An[16], wreg[16];
#pragma unroll
  for (int j = 0; j < 4; ++j) {
    f32x4 a = *(const f32x4*)&A_log[d * 16 + j * 4];
    f32x4 w = *(const f32x4*)&dtw[d * 16 + j * 4];
#pragma unroll
    for (int q = 0; q < 4; ++q) { An[j * 4 + q] = -__expf(a[q]); wreg[j * 4 + q] = w[q]; }
  }
  const float bd = dtb[d];
  float P[16], S[16];
#pragma unroll
  for (int n = 0; n < 16; ++n) { P[n] = 1.f; S[n] = 0.f; }
  __syncthreads();

  const size_t rowbase = ((size_t)b * LL + (size_t)c * CHUNK) * DI + d;
  float ut = u[rowbase];
  for (int t = 0; t < CHUNK; ++t) {
    const float ut_n = (t + 1 < CHUNK) ? u[rowbase + (size_t)(t + 1) * DI] : 0.f;
    float a = bd;
#pragma unroll
    for (int k2 = 0; k2 < 16; ++k2) a = fmaf(sdt[t][k2], wreg[k2], a);
    const float dt = (a > 15.f) ? a : log1pf(__expf(a));
    const float k = dt * ut;
#pragma unroll
    for (int n = 0; n < 16; ++n) {
      const float dA = __expf(dt * An[n]);
      S[n] = fmaf(dA, S[n], k * sB[t][n]);
      P[n] *= dA;
    }
    ut = ut_n;
  }
  float* Pp = Pw + ((size_t)c * BDN) + ((size_t)b * DI + d) * 16;
  float* Sp = Sw + ((size_t)c * BDN) + ((size_t)b * DI + d) * 16;
#pragma unroll
  for (int j = 0; j < 4; ++j) {
    f32x4 pv, sv;
#pragma unroll
    for (int q = 0; q < 4; ++q) { pv[q] = P[j * 4 + q]; sv[q] = S[j * 4 + q]; }
    *(f32x4*)&Pp[j * 4] = pv;
    *(f32x4*)&Sp[j * 4] = sv;
  }
}

// Pass 2: inter-chunk scan; writes Hstart[c] in place over Pw.
__global__ void k_scan2(float* __restrict__ Pw, const float* __restrict__ Sw) {
  const int f = blockIdx.x * 256 + threadIdx.x;   // [0, BDN)
  float h = 0.f;
#pragma unroll 4
  for (int c = 0; c < NCHUNK; ++c) {
    const float Pc = Pw[(size_t)c * BDN + f];
    const float Sc = Sw[(size_t)c * BDN + f];
    Pw[(size_t)c * BDN + f] = h;
    h = fmaf(Pc, h, Sc);
  }
}

// Pass 3: replay from Hstart; y = sum_n h*C, fused +u*D, silu(z), bf16 store.
__global__ __launch_bounds__(256)
void k_scan3(const float* __restrict__ u, const float* __restrict__ xdbl,
             const float* __restrict__ xz, const float* __restrict__ A_log,
             const float* __restrict__ dtw, const float* __restrict__ dtb,
             const float* __restrict__ Dp,
             const float* __restrict__ Hs, ushort* __restrict__ y_bf) {
  const int c = blockIdx.x;
  const int b = blockIdx.y >> 1;
  const int d = ((blockIdx.y & 1) << 8) + threadIdx.x;
  __shared__ float sdt[CHUNK][16], sB[CHUNK][16], sC[CHUNK][16];
  {
    const int i = threadIdx.x * 2;
    const int t = i >> 4, n = i & 15;
    const size_t g = ((size_t)b * LL + (size_t)c * CHUNK + t) * 128 + n;
    *(float2*)&sdt[t][n] = *(const float2*)&xdbl[g];
    *(float2*)&sB[t][n]  = *(const float2*)&xdbl[g + DTR];
    *(float2*)&sC[t][n]  = *(const float2*)&xdbl[g + DTR + NST];
  }
  float An[16], wreg[16];
#pragma unroll
  for (int j = 0; j < 4; ++j) {
    f32x4 a = *(const f32x4*)&A_log[d * 16 + j * 4];
    f32x4 w = *(const f32x4*)&dtw[d * 16 + j * 4];
#pragma unroll
    for (int q = 0; q < 4; ++q) { An[j * 4 + q] = -__expf(a[q]); wreg[j * 4 + q] = w[q]; }
  }
  const float bd = dtb[d];
  float h[16];
  {
    const float* Hp = Hs + ((size_t)c * BDN) + ((size_t)b * DI + d) * 16;
#pragma unroll
    for (int j = 0; j < 4; ++j) {
      f32x4 v = *(const f32x4*)&Hp[j * 4];
#pragma unroll
      for (int q = 0; q < 4; ++q) h[j * 4 + q] = v[q];
    }
  }
  const float Dd = Dp[d];
  __syncthreads();

  const size_t rowbase = ((size_t)b * LL + (size_t)c * CHUNK) * DI + d;
  const size_t zbase   = ((size_t)b * LL + (size_t)c * CHUNK) * 1024 + DI + d;
  float ut = u[rowbase];
  float zt = xz[zbase];
  for (int t = 0; t < CHUNK; ++t) {
    float ut_n = 0.f, zt_n = 0.f;
    if (t + 1 < CHUNK) {
      ut_n = u[rowbase + (size_t)(t + 1) * DI];
      zt_n = xz[zbase + (size_t)(t + 1) * 1024];
    }
    float a = bd;
#pragma unroll
    for (int k2 = 0; k2 < 16; ++k2) a = fmaf(sdt[t][k2], wreg[k2], a);
    const float dt = (a > 15.f) ? a : log1pf(__expf(a));
    const float k = dt * ut;
    float y = 0.f;
#pragma unroll
    for (int n = 0; n < 16; ++n) {
      const float dA = __expf(dt * An[n]);
      h[n] = fmaf(dA, h[n], k * sB[t][n]);
      y = fmaf(h[n], sC[t][n], y);
    }
    y = (y + ut * Dd) * (zt / (1.f + __expf(-zt)));
    y_bf[rowbase + (size_t)t * DI] = f2bf(y);
    ut = ut_n; zt = zt_n;
  }
}

// ---------------------------------------------------------------------------
extern "C" void kernel_launch(void* const* d_in, const int* in_sizes, int n_in,
                              void* d_out, int out_size, void* d_ws, size_t ws_size,
                              hipStream_t stream) {
  const float* x          = (const float*)d_in[0];
  const float* in_proj_w  = (const float*)d_in[1];
  const float* conv_w     = (const float*)d_in[2];
  const float* conv_b     = (const float*)d_in[3];
  const float* x_proj_w   = (const float*)d_in[4];
  const float* dt_proj_w  = (const float*)d_in[5];
  const float* dt_proj_b  = (const float*)d_in[6];
  const float* A_log      = (const float*)d_in[7];
  const float* Dp         = (const float*)d_in[8];
  const float* out_proj_w = (const float*)d_in[9];
  const float* lin1_w     = (const float*)d_in[10];
  const float* lin1_b     = (const float*)d_in[11];
  const float* lin2_w     = (const float*)d_in[12];
  const float* lin2_b     = (const float*)d_in[13];
  float* out = (float*)d_out;

  char* p = (char*)d_ws;
  auto carve = [&](size_t bytes) -> char* {
    char* r = p;
    p += (bytes + 255) & ~(size_t)255;
    return r;
  };
  ushort* x_bf   = (ushort*)carve((size_t)ML * DM * 2);
  ushort* wip_bf = (ushort*)carve((size_t)2 * DI * DM * 2);
  float*  xz     = (float*) carve((size_t)ML * 1024 * 4);
  float*  u      = (float*) carve((size_t)ML * DI * 4);
  ushort* u_bf   = (ushort*)carve((size_t)ML * DI * 2);
  ushort* xpw_bf = (ushort*)carve((size_t)128 * DI * 2);
  float*  xdbl   = (float*) carve((size_t)ML * 128 * 4);
  ushort* y_bf   = (ushort*)carve((size_t)ML * DI * 2);
  ushort* opw_bf = (ushort*)carve((size_t)DM * DI * 2);
  ushort* l1w_bf = (ushort*)carve((size_t)DFF * DM * 2);
  float*  Pws    = (float*) carve((size_t)NCHUNK * BDN * 4);   // 8 MB (then Hstart)
  float*  Sws    = (float*) carve((size_t)NCHUNK * BDN * 4);   // 8 MB
  // lifetime-disjoint aliases (all writes happen after the donor's last read):
  ushort* m_bf   = u_bf;            // u_bf last read by x_proj gemm
  ushort* h1_bf  = (ushort*)xz;     // xz last read by scan3 (z)
  ushort* l2w_bf = (ushort*)u;      // u last read by scan3

  // 1) convert x and in_proj_w to bf16
  k_f2b<<<(ML * DM / 4 + 255) / 256, 256, 0, stream>>>(x, x_bf, ML * DM / 4);
  k_f2b<<<(2 * DI * DM / 4 + 255) / 256, 256, 0, stream>>>(in_proj_w, wip_bf, 2 * DI * DM / 4);
  // 2) xz = x @ in_proj_w^T   (M=8192, N=1024, K=256)  -> f32
  k_gemm<1, 0, 0, 0><<<dim3(1024 / 128, ML / 128), 256, 0, stream>>>(
      x_bf, wip_bf, nullptr, xz, nullptr, ML, 1024, DM);
  // 3) causal conv + SiLU -> u (f32 + bf16)
  k_conv<<<(ML * DI / 4 + 255) / 256, 256, 0, stream>>>(xz, conv_w, conv_b, u, u_bf);
  // 4) x_dbl = u @ x_proj_w^T (N padded 48->128, zero rows)  -> f32
  k_xprojw<<<(128 * DI / 4 + 255) / 256, 256, 0, stream>>>(x_proj_w, xpw_bf);
  k_gemm<1, 0, 0, 0><<<dim3(1, ML / 128), 256, 0, stream>>>(
      u_bf, xpw_bf, nullptr, xdbl, nullptr, ML, 128, DI);
  // 5) chunked selective scan (inline softplus(dt-proj)) + gating -> y_bf
  k_scan1<<<dim3(NCHUNK, BB * 2), 256, 0, stream>>>(u, xdbl, A_log, dt_proj_w,
                                                    dt_proj_b, Pws, Sws);
  k_scan2<<<BDN / 256, 256, 0, stream>>>(Pws, Sws);
  k_scan3<<<dim3(NCHUNK, BB * 2), 256, 0, stream>>>(u, xdbl, xz, A_log, dt_proj_w,
                                                    dt_proj_b, Dp, Pws, y_bf);
  // 6) m = y @ out_proj_w^T (N=256, K=512) -> bf16
  k_f2b<<<(DM * DI / 4 + 255) / 256, 256, 0, stream>>>(out_proj_w, opw_bf, DM * DI / 4);
  k_gemm<0, 1, 0, 0><<<dim3(DM / 128, ML / 128), 256, 0, stream>>>(
      y_bf, opw_bf, nullptr, nullptr, m_bf, ML, DM, DI);
  // 7) h1 = relu(m @ lin1_w^T + b1) (M=8192, N=2048, K=256) -> bf16  [256² kernel]
  k_f2b<<<(DFF * DM / 4 + 255) / 256, 256, 0, stream>>>(lin1_w, l1w_bf, DFF * DM / 4);
  k_gemm256<0, 1, 1, 1><<<dim3(DFF / 256, ML / 256), 512, 0, stream>>>(
      m_bf, l1w_bf, lin1_b, nullptr, h1_bf, ML, DFF, DM);
  // 8) out = h1 @ lin2_w^T + b2 (M=8192, N=2048, K=2048) -> f32  [256² kernel]
  k_f2b<<<(DFF * DFF / 4 + 255) / 256, 256, 0, stream>>>(lin2_w, l2w_bf, DFF * DFF / 4);
  k_gemm256<1, 0, 1, 0><<<dim3(DFF / 256, ML / 256), 512, 0, stream>>>(
      h1_bf, l2w_bf, lin2_b, out, nullptr, ML, DFF, DFF);
}

// Round 13
// 345.111 us; speedup vs baseline: 3.9596x; 1.0707x over previous
//
#include <hip/hip_runtime.h>
#include <hip/hip_bf16.h>
#include <stdint.h>

#define BB  2
#define LL  4096
#define DM  256
#define DI  512
#define NST 16
#define DTR 16
#define DFF 2048
#define ML  (BB*LL)   // 8192 rows

#define NCHUNK 128
#define CHUNK  32     // NCHUNK*CHUNK == LL
#define BDN    (BB*DI*NST)   // 16384

typedef __attribute__((ext_vector_type(8))) short s16x8;
typedef __attribute__((ext_vector_type(4))) float f32x4;

__device__ __forceinline__ ushort f2bf(float f) {
  union { float f; uint32_t u; } v; v.f = f;
  return (ushort)((v.u + 0x7FFFu + ((v.u >> 16) & 1u)) >> 16);  // RNE
}

__device__ __forceinline__ void async16(const void* g, void* l) {
  __builtin_amdgcn_global_load_lds(
      (const __attribute__((address_space(1))) void*)g,
      (__attribute__((address_space(3))) void*)l, 16, 0, 0);
}

// ---------------- generic f32 -> bf16 convert (n4 = count/4) ----------------
__global__ void k_f2b(const float* __restrict__ src, ushort* __restrict__ dst, int n4) {
  int i = blockIdx.x * 256 + threadIdx.x;
  if (i >= n4) return;
  f32x4 v = ((const f32x4*)src)[i];
  *(ushort4*)&dst[i * 4] = make_ushort4(f2bf(v[0]), f2bf(v[1]), f2bf(v[2]), f2bf(v[3]));
}

// ---------------- x_proj_w [48][512] -> padded bf16 [128][512] --------------
__global__ void k_xprojw(const float* __restrict__ src, ushort* __restrict__ dst) {
  int i = blockIdx.x * 256 + threadIdx.x;         // ushort4 groups: 128*512/4
  if (i >= 128 * DI / 4) return;
  int e = i * 4;
  int r = e >> 9;          // /512
  int c = e & 511;
  ushort4 o;
  if (r < DTR + 2 * NST) {
    f32x4 v = *(const f32x4*)&src[r * DI + c];
    o = make_ushort4(f2bf(v[0]), f2bf(v[1]), f2bf(v[2]), f2bf(v[3]));
  } else {
    o = make_ushort4(0, 0, 0, 0);
  }
  *(ushort4*)&dst[e] = o;
}

// ---------------- 128x128 bf16 MFMA GEMM (small-N shapes) -------------------
// 3-buffer LDS pipeline, counted vmcnt(4); swizzle s(r)=(r>>1)&3 (2-way, free).
template<int OUTF, int OUTB, int BIAS, int RELU>
__global__ __launch_bounds__(256)
void k_gemm(const ushort* __restrict__ A, const ushort* __restrict__ W,
            const float* __restrict__ bias,
            float* __restrict__ outF, ushort* __restrict__ outB,
            int M, int N, int K) {
  __shared__ __align__(16) ushort AsB[3][128 * 32];
  __shared__ __align__(16) ushort BsB[3][128 * 32];
  const int tid  = threadIdx.x;
  const int lane = tid & 63;
  const int wv   = tid >> 6;

  const int nwg  = gridDim.x * gridDim.y;
  const int flat = blockIdx.y * gridDim.x + blockIdx.x;
  const int cpx  = nwg >> 3;
  const int swz  = (nwg & 7) ? flat : (flat & 7) * cpx + (flat >> 3);
  const int m0 = (swz / gridDim.x) << 7;
  const int n0 = (swz % gridDim.x) << 7;

  const int wr = (wv >> 1) << 6;
  const int wc = (wv & 1) << 6;
  const int lr = lane & 15;
  const int hi = lane >> 4;

  f32x4 acc[4][4] = {};

  const int sr0 = (wv << 5) + (lane >> 2);
  const int sc  = lane & 3;
  const int nt = K >> 5;

  auto STAGE = [&](int t, int bi) {
    const int k0 = t << 5;
#pragma unroll
    for (int j = 0; j < 2; ++j) {
      const int r  = sr0 + j * 16;
      const int cs = sc ^ ((r >> 1) & 3);
      async16(A + (size_t)(m0 + r) * K + k0 + cs * 8, &AsB[bi][((wv << 5) + j * 16) * 32]);
      async16(W + (size_t)(n0 + r) * K + k0 + cs * 8, &BsB[bi][((wv << 5) + j * 16) * 32]);
    }
  };

  STAGE(0, 0);
  STAGE(1, 1);

  int cur = 0;
  for (int t = 0; t < nt; ++t) {
    if (t + 1 < nt) { asm volatile("s_waitcnt vmcnt(4)" ::: "memory"); }
    else            { asm volatile("s_waitcnt vmcnt(0)" ::: "memory"); }
    __builtin_amdgcn_s_barrier();
    __builtin_amdgcn_sched_barrier(0);

    if (t + 2 < nt) {
      int nx2 = cur + 2; if (nx2 >= 3) nx2 -= 3;
      STAGE(t + 2, nx2);
    }

    const ushort* As = AsB[cur];
    const ushort* Bs = BsB[cur];
    s16x8 af[4], bf_[4];
#pragma unroll
    for (int mi = 0; mi < 4; ++mi) {
      const int row = wr + mi * 16 + lr;
      af[mi] = *(const s16x8*)&As[row * 32 + ((hi ^ ((row >> 1) & 3)) << 3)];
    }
#pragma unroll
    for (int ni = 0; ni < 4; ++ni) {
      const int row = wc + ni * 16 + lr;
      bf_[ni] = *(const s16x8*)&Bs[row * 32 + ((hi ^ ((row >> 1) & 3)) << 3)];
    }
    asm volatile("s_waitcnt lgkmcnt(0)" ::: "memory");
    __builtin_amdgcn_sched_barrier(0);

    __builtin_amdgcn_s_setprio(1);
#pragma unroll
    for (int mi = 0; mi < 4; ++mi)
#pragma unroll
      for (int ni = 0; ni < 4; ++ni)
        acc[mi][ni] = __builtin_amdgcn_mfma_f32_16x16x32_bf16(af[mi], bf_[ni], acc[mi][ni], 0, 0, 0);
    __builtin_amdgcn_s_setprio(0);

    cur = (cur + 1 == 3) ? 0 : cur + 1;
  }

#pragma unroll
  for (int mi = 0; mi < 4; ++mi) {
#pragma unroll
    for (int ni = 0; ni < 4; ++ni) {
      const int gc = n0 + wc + ni * 16 + lr;
      const float b = BIAS ? bias[gc] : 0.f;
#pragma unroll
      for (int i = 0; i < 4; ++i) {
        const int gr = m0 + wr + mi * 16 + (hi << 2) + i;
        float v = acc[mi][ni][i] + b;
        if (RELU) v = fmaxf(v, 0.f);
        if (OUTF) outF[(size_t)gr * N + gc] = v;
        if (OUTB) outB[(size_t)gr * N + gc] = f2bf(v);
      }
    }
  }
}

// ---------------- 256x256 bf16 MFMA GEMM (lin1/lin2, N>=2048) ---------------
// 512 thr = 8 waves (2M x 4N), per-wave 128x64 output, BK=32.
// 4-buffer LDS ring + CROSS-STEP REGISTER DOUBLE-BUFFER: unroll-by-2 with two
// named fragment sets; each half does
//   vmcnt(ladder) ; lgkmcnt(0) ; barrier ; ds_read(next tile -> other set) ;
//   STAGE(t+4) ; sched_barrier ; MFMA(current set) ; sched_barrier
// so ds_read latency of tile t+1 hides under tile t's 32 MFMAs.
// Hazards: lgkmcnt(0) precedes every barrier => all waves' reads of a buffer
// retire before any re-STAGE of it (WAR safe); vmcnt ladder (8/4/0 by tiles
// remaining) publishes tile t+1's gloads before its ds_read (RAW safe).
template<int OUTF, int OUTB, int BIAS, int RELU>
__global__ __launch_bounds__(512, 2)
void k_gemm256(const ushort* __restrict__ A, const ushort* __restrict__ W,
               const float* __restrict__ bias,
               float* __restrict__ outF, ushort* __restrict__ outB,
               int M, int N, int K) {
  __shared__ __align__(16) ushort AsB[4][256 * 32];  // 64 KiB
  __shared__ __align__(16) ushort BsB[4][256 * 32];  // 64 KiB
  const int tid  = threadIdx.x;
  const int lane = tid & 63;
  const int wv   = tid >> 6;          // 0..7

  const int nwg  = gridDim.x * gridDim.y;
  const int flat = blockIdx.y * gridDim.x + blockIdx.x;
  const int cpx  = nwg >> 3;
  const int swz  = (nwg & 7) ? flat : (flat & 7) * cpx + (flat >> 3);
  const int m0 = (swz / gridDim.x) << 8;
  const int n0 = (swz % gridDim.x) << 8;

  const int wrM = (wv >> 2) << 7;     // 0 / 128
  const int wcN = (wv & 3) << 6;      // 0 / 64 / 128 / 192
  const int lr = lane & 15;
  const int hi = lane >> 4;

  f32x4 acc[8][4] = {};

  const int sr0 = (wv << 5) + (lane >> 2);   // this wave stages rows wv*32..+31
  const int sc  = lane & 3;
  const int nt  = K >> 5;                    // even for all uses (8, 64)

  auto STAGE = [&](int t, int bi) {
    const int k0 = t << 5;
#pragma unroll
    for (int j = 0; j < 2; ++j) {
      const int r  = sr0 + j * 16;
      const int cs = sc ^ ((r >> 1) & 3);    // pre-swizzled global source chunk
      async16(A + (size_t)(m0 + r) * K + k0 + cs * 8, &AsB[bi][((wv << 5) + j * 16) * 32]);
      async16(W + (size_t)(n0 + r) * K + k0 + cs * 8, &BsB[bi][((wv << 5) + j * 16) * 32]);
    }
  };

  // fragment read: 12 ds_read_b128 into a named set (no wait here)
  auto DSREAD = [&](s16x8 (&af)[8], s16x8 (&bf_)[4], int bi) {
    const ushort* As = AsB[bi];
    const ushort* Bs = BsB[bi];
#pragma unroll
    for (int ni = 0; ni < 4; ++ni) {
      const int row = wcN + ni * 16 + lr;
      bf_[ni] = *(const s16x8*)&Bs[row * 32 + ((hi ^ ((row >> 1) & 3)) << 3)];
    }
#pragma unroll
    for (int mi = 0; mi < 8; ++mi) {
      const int row = wrM + mi * 16 + lr;
      af[mi] = *(const s16x8*)&As[row * 32 + ((hi ^ ((row >> 1) & 3)) << 3)];
    }
  };

  auto MFMA = [&](s16x8 (&af)[8], s16x8 (&bf_)[4]) {
    __builtin_amdgcn_s_setprio(1);
#pragma unroll
    for (int mi = 0; mi < 8; ++mi)
#pragma unroll
      for (int ni = 0; ni < 4; ++ni)
        acc[mi][ni] = __builtin_amdgcn_mfma_f32_16x16x32_bf16(af[mi], bf_[ni], acc[mi][ni], 0, 0, 0);
    __builtin_amdgcn_s_setprio(0);
    __builtin_amdgcn_sched_barrier(0);
  };

  auto WAITV = [&](int tiles_beyond) {   // vmcnt ladder: 4 loads/wave/tile
    if (tiles_beyond >= 2)      { asm volatile("s_waitcnt vmcnt(8)" ::: "memory"); }
    else if (tiles_beyond == 1) { asm volatile("s_waitcnt vmcnt(4)" ::: "memory"); }
    else                        { asm volatile("s_waitcnt vmcnt(0)" ::: "memory"); }
  };

  s16x8 afE[8], bfE[4];   // even-tile fragment set
  s16x8 afO[8], bfO[4];   // odd-tile fragment set

  // prologue: stage 0..2, publish tile 0, read its fragments, stage 3
  STAGE(0, 0);
  STAGE(1, 1);
  STAGE(2, 2);
  WAITV(2);                      // tile 0 landed (tiles 1,2 in flight)
  __builtin_amdgcn_s_barrier();
  DSREAD(afE, bfE, 0);
  STAGE(3, 3);
  __builtin_amdgcn_sched_barrier(0);

  for (int s = 0; s < nt; s += 2) {
    // ---- half A: compute tile s (even set); fetch tile s+1 into odd set ----
    WAITV(nt - 2 - s);           // ensure tile s+1's gloads landed
    asm volatile("s_waitcnt lgkmcnt(0)" ::: "memory");   // drain own ds_reads
    __builtin_amdgcn_s_barrier();
    __builtin_amdgcn_sched_barrier(0);
    if (s + 1 < nt) DSREAD(afO, bfO, (s + 1) & 3);
    if (s + 4 < nt) STAGE(s + 4, (s + 4) & 3);
    __builtin_amdgcn_sched_barrier(0);
    MFMA(afE, bfE);

    // ---- half B: compute tile s+1 (odd set); fetch tile s+2 into even set --
    WAITV(nt - 3 - s);           // ensure tile s+2's gloads landed
    asm volatile("s_waitcnt lgkmcnt(0)" ::: "memory");
    __builtin_amdgcn_s_barrier();
    __builtin_amdgcn_sched_barrier(0);
    if (s + 2 < nt) DSREAD(afE, bfE, (s + 2) & 3);
    if (s + 5 < nt) STAGE(s + 5, (s + 5) & 3);
    __builtin_amdgcn_sched_barrier(0);
    MFMA(afO, bfO);
  }

#pragma unroll
  for (int mi = 0; mi < 8; ++mi) {
#pragma unroll
    for (int ni = 0; ni < 4; ++ni) {
      const int gc = n0 + wcN + ni * 16 + lr;
      const float b = BIAS ? bias[gc] : 0.f;
#pragma unroll
      for (int i = 0; i < 4; ++i) {
        const int gr = m0 + wrM + mi * 16 + (hi << 2) + i;
        float v = acc[mi][ni][i] + b;
        if (RELU) v = fmaxf(v, 0.f);
        if (OUTF) outF[(size_t)gr * N + gc] = v;
        if (OUTB) outB[(size_t)gr * N + gc] = f2bf(v);
      }
    }
  }
}

// ---------------- causal depthwise conv (k=4) + SiLU ------------------------
__global__ void k_conv(const float* __restrict__ xz, const float* __restrict__ cw,
                       const float* __restrict__ cb,
                       float* __restrict__ u, ushort* __restrict__ u_bf) {
  const int i = blockIdx.x * 256 + threadIdx.x;    // over ML*DI/4
  if (i >= ML * DI / 4) return;
  const int d4 = i & (DI / 4 - 1);
  const int bl = i / (DI / 4);
  const int l  = bl & (LL - 1);
  const int d  = d4 << 2;
  f32x4 acc;
  acc[0] = cb[d]; acc[1] = cb[d + 1]; acc[2] = cb[d + 2]; acc[3] = cb[d + 3];
#pragma unroll
  for (int j = 0; j < 4; ++j) {
    const int lj = l - 3 + j;
    if (lj >= 0) {
      const f32x4 xv = *(const f32x4*)&xz[(size_t)(bl + j - 3) * 1024 + d];
      acc[0] += xv[0] * cw[(d + 0) * 4 + j];
      acc[1] += xv[1] * cw[(d + 1) * 4 + j];
      acc[2] += xv[2] * cw[(d + 2) * 4 + j];
      acc[3] += xv[3] * cw[(d + 3) * 4 + j];
    }
  }
  f32x4 o;
#pragma unroll
  for (int c = 0; c < 4; ++c) o[c] = acc[c] / (1.f + __expf(-acc[c]));
  *(f32x4*)&u[(size_t)bl * DI + d] = o;
  *(ushort4*)&u_bf[(size_t)bl * DI + d] =
      make_ushort4(f2bf(o[0]), f2bf(o[1]), f2bf(o[2]), f2bf(o[3]));
}

// ======================= chunked parallel selective scan ====================
// delta = softplus(dt_row @ dt_proj_w^T + b) computed INLINE in both passes.
__global__ __launch_bounds__(256)
void k_scan1(const float* __restrict__ u, const float* __restrict__ xdbl,
             const float* __restrict__ A_log, const float* __restrict__ dtw,
             const float* __restrict__ dtb,
             float* __restrict__ Pw, float* __restrict__ Sw) {
  const int c = blockIdx.x;
  const int b = blockIdx.y >> 1;
  const int d = ((blockIdx.y & 1) << 8) + threadIdx.x;
  __shared__ float sdt[CHUNK][16], sB[CHUNK][16];
  {
    const int i = threadIdx.x * 2;            // 512 floats each
    const int t = i >> 4, n = i & 15;
    const size_t g = ((size_t)b * LL + (size_t)c * CHUNK + t) * 128 + n;
    *(float2*)&sdt[t][n] = *(const float2*)&xdbl[g];
    *(float2*)&sB[t][n]  = *(const float2*)&xdbl[g + DTR];
  }
  float An[16], wreg[16];
#pragma unroll
  for (int j = 0; j < 4; ++j) {
    f32x4 a = *(const f32x4*)&A_log[d * 16 + j * 4];
    f32x4 w = *(const f32x4*)&dtw[d * 16 + j * 4];
#pragma unroll
    for (int q = 0; q < 4; ++q) { An[j * 4 + q] = -__expf(a[q]); wreg[j * 4 + q] = w[q]; }
  }
  const float bd = dtb[d];
  float P[16], S[16];
#pragma unroll
  for (int n = 0; n < 16; ++n) { P[n] = 1.f; S[n] = 0.f; }
  __syncthreads();

  const size_t rowbase = ((size_t)b * LL + (size_t)c * CHUNK) * DI + d;
  float ut = u[rowbase];
  for (int t = 0; t < CHUNK; ++t) {
    const float ut_n = (t + 1 < CHUNK) ? u[rowbase + (size_t)(t + 1) * DI] : 0.f;
    float a = bd;
#pragma unroll
    for (int k2 = 0; k2 < 16; ++k2) a = fmaf(sdt[t][k2], wreg[k2], a);
    const float dt = (a > 15.f) ? a : log1pf(__expf(a));
    const float k = dt * ut;
#pragma unroll
    for (int n = 0; n < 16; ++n) {
      const float dA = __expf(dt * An[n]);
      S[n] = fmaf(dA, S[n], k * sB[t][n]);
      P[n] *= dA;
    }
    ut = ut_n;
  }
  float* Pp = Pw + ((size_t)c * BDN) + ((size_t)b * DI + d) * 16;
  float* Sp = Sw + ((size_t)c * BDN) + ((size_t)b * DI + d) * 16;
#pragma unroll
  for (int j = 0; j < 4; ++j) {
    f32x4 pv, sv;
#pragma unroll
    for (int q = 0; q < 4; ++q) { pv[q] = P[j * 4 + q]; sv[q] = S[j * 4 + q]; }
    *(f32x4*)&Pp[j * 4] = pv;
    *(f32x4*)&Sp[j * 4] = sv;
  }
}

// Pass 2: inter-chunk scan; writes Hstart[c] in place over Pw.
__global__ void k_scan2(float* __restrict__ Pw, const float* __restrict__ Sw) {
  const int f = blockIdx.x * 256 + threadIdx.x;   // [0, BDN)
  float h = 0.f;
#pragma unroll 4
  for (int c = 0; c < NCHUNK; ++c) {
    const float Pc = Pw[(size_t)c * BDN + f];
    const float Sc = Sw[(size_t)c * BDN + f];
    Pw[(size_t)c * BDN + f] = h;
    h = fmaf(Pc, h, Sc);
  }
}

// Pass 3: replay from Hstart; y = sum_n h*C, fused +u*D, silu(z), bf16 store.
__global__ __launch_bounds__(256)
void k_scan3(const float* __restrict__ u, const float* __restrict__ xdbl,
             const float* __restrict__ xz, const float* __restrict__ A_log,
             const float* __restrict__ dtw, const float* __restrict__ dtb,
             const float* __restrict__ Dp,
             const float* __restrict__ Hs, ushort* __restrict__ y_bf) {
  const int c = blockIdx.x;
  const int b = blockIdx.y >> 1;
  const int d = ((blockIdx.y & 1) << 8) + threadIdx.x;
  __shared__ float sdt[CHUNK][16], sB[CHUNK][16], sC[CHUNK][16];
  {
    const int i = threadIdx.x * 2;
    const int t = i >> 4, n = i & 15;
    const size_t g = ((size_t)b * LL + (size_t)c * CHUNK + t) * 128 + n;
    *(float2*)&sdt[t][n] = *(const float2*)&xdbl[g];
    *(float2*)&sB[t][n]  = *(const float2*)&xdbl[g + DTR];
    *(float2*)&sC[t][n]  = *(const float2*)&xdbl[g + DTR + NST];
  }
  float An[16], wreg[16];
#pragma unroll
  for (int j = 0; j < 4; ++j) {
    f32x4 a = *(const f32x4*)&A_log[d * 16 + j * 4];
    f32x4 w = *(const f32x4*)&dtw[d * 16 + j * 4];
#pragma unroll
    for (int q = 0; q < 4; ++q) { An[j * 4 + q] = -__expf(a[q]); wreg[j * 4 + q] = w[q]; }
  }
  const float bd = dtb[d];
  float h[16];
  {
    const float* Hp = Hs + ((size_t)c * BDN) + ((size_t)b * DI + d) * 16;
#pragma unroll
    for (int j = 0; j < 4; ++j) {
      f32x4 v = *(const f32x4*)&Hp[j * 4];
#pragma unroll
      for (int q = 0; q < 4; ++q) h[j * 4 + q] = v[q];
    }
  }
  const float Dd = Dp[d];
  __syncthreads();

  const size_t rowbase = ((size_t)b * LL + (size_t)c * CHUNK) * DI + d;
  const size_t zbase   = ((size_t)b * LL + (size_t)c * CHUNK) * 1024 + DI + d;
  float ut = u[rowbase];
  float zt = xz[zbase];
  for (int t = 0; t < CHUNK; ++t) {
    float ut_n = 0.f, zt_n = 0.f;
    if (t + 1 < CHUNK) {
      ut_n = u[rowbase + (size_t)(t + 1) * DI];
      zt_n = xz[zbase + (size_t)(t + 1) * 1024];
    }
    float a = bd;
#pragma unroll
    for (int k2 = 0; k2 < 16; ++k2) a = fmaf(sdt[t][k2], wreg[k2], a);
    const float dt = (a > 15.f) ? a : log1pf(__expf(a));
    const float k = dt * ut;
    float y = 0.f;
#pragma unroll
    for (int n = 0; n < 16; ++n) {
      const float dA = __expf(dt * An[n]);
      h[n] = fmaf(dA, h[n], k * sB[t][n]);
      y = fmaf(h[n], sC[t][n], y);
    }
    y = (y + ut * Dd) * (zt / (1.f + __expf(-zt)));
    y_bf[rowbase + (size_t)t * DI] = f2bf(y);
    ut = ut_n; zt = zt_n;
  }
}

// ---------------------------------------------------------------------------
extern "C" void kernel_launch(void* const* d_in, const int* in_sizes, int n_in,
                              void* d_out, int out_size, void* d_ws, size_t ws_size,
                              hipStream_t stream) {
  const float* x          = (const float*)d_in[0];
  const float* in_proj_w  = (const float*)d_in[1];
  const float* conv_w     = (const float*)d_in[2];
  const float* conv_b     = (const float*)d_in[3];
  const float* x_proj_w   = (const float*)d_in[4];
  const float* dt_proj_w  = (const float*)d_in[5];
  const float* dt_proj_b  = (const float*)d_in[6];
  const float* A_log      = (const float*)d_in[7];
  const float* Dp         = (const float*)d_in[8];
  const float* out_proj_w = (const float*)d_in[9];
  const float* lin1_w     = (const float*)d_in[10];
  const float* lin1_b     = (const float*)d_in[11];
  const float* lin2_w     = (const float*)d_in[12];
  const float* lin2_b     = (const float*)d_in[13];
  float* out = (float*)d_out;

  char* p = (char*)d_ws;
  auto carve = [&](size_t bytes) -> char* {
    char* r = p;
    p += (bytes + 255) & ~(size_t)255;
    return r;
  };
  ushort* x_bf   = (ushort*)carve((size_t)ML * DM * 2);
  ushort* wip_bf = (ushort*)carve((size_t)2 * DI * DM * 2);
  float*  xz     = (float*) carve((size_t)ML * 1024 * 4);
  float*  u      = (float*) carve((size_t)ML * DI * 4);
  ushort* u_bf   = (ushort*)carve((size_t)ML * DI * 2);
  ushort* xpw_bf = (ushort*)carve((size_t)128 * DI * 2);
  float*  xdbl   = (float*) carve((size_t)ML * 128 * 4);
  ushort* y_bf   = (ushort*)carve((size_t)ML * DI * 2);
  ushort* opw_bf = (ushort*)carve((size_t)DM * DI * 2);
  ushort* l1w_bf = (ushort*)carve((size_t)DFF * DM * 2);
  float*  Pws    = (float*) carve((size_t)NCHUNK * BDN * 4);   // 8 MB (then Hstart)
  float*  Sws    = (float*) carve((size_t)NCHUNK * BDN * 4);   // 8 MB
  // lifetime-disjoint aliases (all writes happen after the donor's last read):
  ushort* m_bf   = u_bf;            // u_bf last read by x_proj gemm
  ushort* h1_bf  = (ushort*)xz;     // xz last read by scan3 (z)
  ushort* l2w_bf = (ushort*)u;      // u last read by scan3

  // 1) convert x and in_proj_w to bf16
  k_f2b<<<(ML * DM / 4 + 255) / 256, 256, 0, stream>>>(x, x_bf, ML * DM / 4);
  k_f2b<<<(2 * DI * DM / 4 + 255) / 256, 256, 0, stream>>>(in_proj_w, wip_bf, 2 * DI * DM / 4);
  // 2) xz = x @ in_proj_w^T   (M=8192, N=1024, K=256)  -> f32
  k_gemm<1, 0, 0, 0><<<dim3(1024 / 128, ML / 128), 256, 0, stream>>>(
      x_bf, wip_bf, nullptr, xz, nullptr, ML, 1024, DM);
  // 3) causal conv + SiLU -> u (f32 + bf16)
  k_conv<<<(ML * DI / 4 + 255) / 256, 256, 0, stream>>>(xz, conv_w, conv_b, u, u_bf);
  // 4) x_dbl = u @ x_proj_w^T (N padded 48->128, zero rows)  -> f32
  k_xprojw<<<(128 * DI / 4 + 255) / 256, 256, 0, stream>>>(x_proj_w, xpw_bf);
  k_gemm<1, 0, 0, 0><<<dim3(1, ML / 128), 256, 0, stream>>>(
      u_bf, xpw_bf, nullptr, xdbl, nullptr, ML, 128, DI);
  // 5) chunked selective scan (inline softplus(dt-proj)) + gating -> y_bf
  k_scan1<<<dim3(NCHUNK, BB * 2), 256, 0, stream>>>(u, xdbl, A_log, dt_proj_w,
                                                    dt_proj_b, Pws, Sws);
  k_scan2<<<BDN / 256, 256, 0, stream>>>(Pws, Sws);
  k_scan3<<<dim3(NCHUNK, BB * 2), 256, 0, stream>>>(u, xdbl, xz, A_log, dt_proj_w,
                                                    dt_proj_b, Dp, Pws, y_bf);
  // 6) m = y @ out_proj_w^T (N=256, K=512) -> bf16
  k_f2b<<<(DM * DI / 4 + 255) / 256, 256, 0, stream>>>(out_proj_w, opw_bf, DM * DI / 4);
  k_gemm<0, 1, 0, 0><<<dim3(DM / 128, ML / 128), 256, 0, stream>>>(
      y_bf, opw_bf, nullptr, nullptr, m_bf, ML, DM, DI);
  // 7) h1 = relu(m @ lin1_w^T + b1) (M=8192, N=2048, K=256) -> bf16  [256² kernel]
  k_f2b<<<(DFF * DM / 4 + 255) / 256, 256, 0, stream>>>(lin1_w, l1w_bf, DFF * DM / 4);
  k_gemm256<0, 1, 1, 1><<<dim3(DFF / 256, ML / 256), 512, 0, stream>>>(
      m_bf, l1w_bf, lin1_b, nullptr, h1_bf, ML, DFF, DM);
  // 8) out = h1 @ lin2_w^T + b2 (M=8192, N=2048, K=2048) -> f32  [256² kernel]
  k_f2b<<<(DFF * DFF / 4 + 255) / 256, 256, 0, stream>>>(lin2_w, l2w_bf, DFF * DFF / 4);
  k_gemm256<1, 0, 1, 0><<<dim3(DFF / 256, ML / 256), 512, 0, stream>>>(
      h1_bf, l2w_bf, lin2_b, out, nullptr, ML, DFF, DFF);
}